// Round 1
// baseline (1949.924 us; speedup 1.0000x reference)
//
#include <hip/hip_runtime.h>
#include <math.h>

namespace {

constexpr int B = 8, T = 2048, D = 256, H = 4, HD = 64, FF = 1024;

__device__ __forceinline__ float dot4(float4 a, float4 b) {
    return a.x*b.x + a.y*b.y + a.z*b.z + a.w*b.w;
}

// ---------------- K1: qkv = x @ Wqkv^T + bqkv, scattered to (B,H,T,hd) ----
__global__ __launch_bounds__(256) void k_qkv(
        const float* __restrict__ x, const float* __restrict__ Wqkv,
        const float* __restrict__ bqkv,
        float* __restrict__ qb, float* __restrict__ kb, float* __restrict__ vb) {
    __shared__ float xs[16][D];
    const int tid = threadIdx.x;
    const size_t row0 = (size_t)blockIdx.x * 16;
    const int b = (int)(row0 >> 11);
    {
        const float4* xg = (const float4*)(x + row0 * D);
        float4* s4 = (float4*)&xs[0][0];
        #pragma unroll
        for (int i = 0; i < 4; i++) s4[tid + i*256] = xg[tid + i*256];
    }
    __syncthreads();
    float a0[16], a1[16], a2[16];
    #pragma unroll
    for (int r = 0; r < 16; r++) { a0[r]=0.f; a1[r]=0.f; a2[r]=0.f; }
    const float4* w0p = (const float4*)(Wqkv + (size_t)tid * D);
    const float4* w1p = (const float4*)(Wqkv + (size_t)(tid+256) * D);
    const float4* w2p = (const float4*)(Wqkv + (size_t)(tid+512) * D);
    for (int d4 = 0; d4 < D/4; d4++) {
        float4 w0 = w0p[d4], w1 = w1p[d4], w2 = w2p[d4];
        #pragma unroll
        for (int r = 0; r < 16; r++) {
            float4 xv = *(const float4*)&xs[r][d4*4];
            a0[r] += dot4(w0, xv);
            a1[r] += dot4(w1, xv);
            a2[r] += dot4(w2, xv);
        }
    }
    const float bq = bqkv[tid], bk = bqkv[tid+256], bv = bqkv[tid+512];
    const int h = tid >> 6, d = tid & 63;
    #pragma unroll
    for (int r = 0; r < 16; r++) {
        const int t = (int)((row0 + r) & (size_t)(T-1));
        const size_t idx = ((size_t)(b*H + h) * T + t) * HD + d;
        qb[idx] = a0[r] + bq;
        kb[idx] = a1[r] + bk;
        vb[idx] = a2[r] + bv;
    }
}

// ---------------- K2: flash attention + column-sum partials ----------------
// block: 256 threads, 32 queries x 64-key tiles. thread = (q = tid>>3, j = tid&7)
// owns scores for keys j*8..j*8+7 and output dims j*8..j*8+7.
__global__ __launch_bounds__(256) void k_flash(
        const float* __restrict__ qb, const float* __restrict__ kb,
        const float* __restrict__ vb, const float* __restrict__ mask,
        float* __restrict__ attnb, float* __restrict__ part) {
    __shared__ float Qs[32][68];   // padded: scalar broadcast reads conflict-free
    __shared__ float Kt[64][68];   // K transposed [d][k], stride 68 keeps b128 reads clean
    __shared__ float Vs[64][64];
    __shared__ float Ps[32][76];   // stride 76 => b128 reads conflict-free
    __shared__ float msk[64];
    const int tid = threadIdx.x;
    const int qt = blockIdx.x, h = blockIdx.y, b = blockIdx.z;
    const int bh = b*H + h;
    {
        const float* qg = qb + ((size_t)bh * T + qt*32) * HD;
        #pragma unroll
        for (int i = 0; i < 2; i++) {
            int c = tid + i*256;
            int r = c >> 4, c4 = c & 15;
            *(float4*)&Qs[r][c4*4] = *(const float4*)(qg + r*HD + c4*4);
        }
    }
    const int q = tid >> 3, j = tid & 7;
    const int kcol = j*8;
    float m = -INFINITY, l = 0.f;
    float o[8];
    #pragma unroll
    for (int i = 0; i < 8; i++) o[i] = 0.f;
    const float* kg0 = kb + (size_t)bh * T * HD;
    const float* vg0 = vb + (size_t)bh * T * HD;
    const float* mg  = mask + (size_t)b * T;

    for (int kt = 0; kt < T/64; kt++) {
        __syncthreads();
        {
            const float* kg = kg0 + (size_t)kt*64*HD;
            const float* vg = vg0 + (size_t)kt*64*HD;
            #pragma unroll
            for (int i = 0; i < 4; i++) {
                int c = tid + i*256;
                int r = c >> 4, c4 = c & 15;
                float4 kv = *(const float4*)(kg + r*HD + c4*4);
                Kt[c4*4+0][r] = kv.x;
                Kt[c4*4+1][r] = kv.y;
                Kt[c4*4+2][r] = kv.z;
                Kt[c4*4+3][r] = kv.w;
                *(float4*)&Vs[r][c4*4] = *(const float4*)(vg + r*HD + c4*4);
            }
            if (tid < 64) msk[tid] = mg[kt*64 + tid];
        }
        __syncthreads();
        float s[8];
        #pragma unroll
        for (int i = 0; i < 8; i++) s[i] = 0.f;
        #pragma unroll 4
        for (int d = 0; d < HD; d++) {
            float qd = Qs[q][d];
            float4 ka = *(const float4*)&Kt[d][kcol];
            float4 kb2 = *(const float4*)&Kt[d][kcol+4];
            s[0] += qd*ka.x;  s[1] += qd*ka.y;  s[2] += qd*ka.z;  s[3] += qd*ka.w;
            s[4] += qd*kb2.x; s[5] += qd*kb2.y; s[6] += qd*kb2.z; s[7] += qd*kb2.w;
        }
        float tm = -INFINITY;
        #pragma unroll
        for (int i = 0; i < 8; i++) {
            s[i] = (msk[kcol+i] > 0.5f) ? -1e9f : s[i]*0.125f;
            tm = fmaxf(tm, s[i]);
        }
        tm = fmaxf(tm, __shfl_xor(tm, 1, 64));
        tm = fmaxf(tm, __shfl_xor(tm, 2, 64));
        tm = fmaxf(tm, __shfl_xor(tm, 4, 64));
        const float mn = fmaxf(m, tm);
        const float corr = __expf(m - mn);   // m=-inf first iter -> 0, safe
        float p[8], ts = 0.f;
        #pragma unroll
        for (int i = 0; i < 8; i++) { p[i] = __expf(s[i] - mn); ts += p[i]; }
        ts += __shfl_xor(ts, 1, 64);
        ts += __shfl_xor(ts, 2, 64);
        ts += __shfl_xor(ts, 4, 64);
        l = l*corr + ts;
        m = mn;
        #pragma unroll
        for (int i = 0; i < 8; i++) o[i] *= corr;
        // exchange p within the 8-lane q-group via LDS (wave-local, no barrier)
        #pragma unroll
        for (int i = 0; i < 4; i++) {
            float2 t2; t2.x = p[2*i]; t2.y = p[2*i+1];
            *(float2*)&Ps[q][kcol + 2*i] = t2;
        }
        #pragma unroll 4
        for (int k4 = 0; k4 < 16; k4++) {
            float4 pv = *(const float4*)&Ps[q][k4*4];
            float pc[4] = {pv.x, pv.y, pv.z, pv.w};
            #pragma unroll
            for (int kk = 0; kk < 4; kk++) {
                float4 v0 = *(const float4*)&Vs[k4*4+kk][kcol];
                float4 v1 = *(const float4*)&Vs[k4*4+kk][kcol+4];
                o[0] += pc[kk]*v0.x; o[1] += pc[kk]*v0.y;
                o[2] += pc[kk]*v0.z; o[3] += pc[kk]*v0.w;
                o[4] += pc[kk]*v1.x; o[5] += pc[kk]*v1.y;
                o[6] += pc[kk]*v1.z; o[7] += pc[kk]*v1.w;
            }
        }
    }
    const float invl = 1.f / l;
    {
        const int t = qt*32 + q;
        float* op = attnb + ((size_t)b*T + t)*D + h*HD + kcol;
        float4 r0, r1;
        r0.x=o[0]*invl; r0.y=o[1]*invl; r0.z=o[2]*invl; r0.w=o[3]*invl;
        r1.x=o[4]*invl; r1.y=o[5]*invl; r1.z=o[6]*invl; r1.w=o[7]*invl;
        *(float4*)op = r0;
        *(float4*)(op+4) = r1;
    }
    // ---- second pass: column sums of normalized weights (for halting) ----
    for (int kt = 0; kt < T/64; kt++) {
        __syncthreads();
        {
            const float* kg = kg0 + (size_t)kt*64*HD;
            #pragma unroll
            for (int i = 0; i < 4; i++) {
                int c = tid + i*256;
                int r = c >> 4, c4 = c & 15;
                float4 kv = *(const float4*)(kg + r*HD + c4*4);
                Kt[c4*4+0][r] = kv.x;
                Kt[c4*4+1][r] = kv.y;
                Kt[c4*4+2][r] = kv.z;
                Kt[c4*4+3][r] = kv.w;
            }
            if (tid < 64) msk[tid] = mg[kt*64 + tid];
        }
        __syncthreads();
        float s[8];
        #pragma unroll
        for (int i = 0; i < 8; i++) s[i] = 0.f;
        #pragma unroll 4
        for (int d = 0; d < HD; d++) {
            float qd = Qs[q][d];
            float4 ka = *(const float4*)&Kt[d][kcol];
            float4 kb2 = *(const float4*)&Kt[d][kcol+4];
            s[0] += qd*ka.x;  s[1] += qd*ka.y;  s[2] += qd*ka.z;  s[3] += qd*ka.w;
            s[4] += qd*kb2.x; s[5] += qd*kb2.y; s[6] += qd*kb2.z; s[7] += qd*kb2.w;
        }
        #pragma unroll
        for (int i = 0; i < 8; i += 2) {
            float s0 = (msk[kcol+i]   > 0.5f) ? -1e9f : s[i]*0.125f;
            float s1 = (msk[kcol+i+1] > 0.5f) ? -1e9f : s[i+1]*0.125f;
            float2 t2;
            t2.x = __expf(s0 - m) * invl;
            t2.y = __expf(s1 - m) * invl;
            *(float2*)&Ps[q][kcol + i] = t2;
        }
        __syncthreads();
        if (tid < 64) {
            float sum = 0.f;
            #pragma unroll 8
            for (int qq = 0; qq < 32; qq++) sum += Ps[qq][tid];
            part[((size_t)(b*256) + h*64 + qt) * T + kt*64 + tid] = sum;
        }
    }
}

// ---------------- K3: halting = softmax(colsum/H + mask*(-1e10)) -----------
__global__ __launch_bounds__(256) void k_halt(
        const float* __restrict__ part, const float* __restrict__ mask,
        float* __restrict__ outh) {
    __shared__ float redm[4], reds[4];
    const int b = blockIdx.x, tid = threadIdx.x;
    float v[8];
    #pragma unroll
    for (int i = 0; i < 8; i++) v[i] = 0.f;
    const float* pb = part + (size_t)b * 256 * T;
    for (int p = 0; p < 256; p++) {
        const float* pp = pb + (size_t)p * T;
        #pragma unroll
        for (int i = 0; i < 8; i++) v[i] += pp[tid + i*256];
    }
    const float* mg = mask + (size_t)b * T;
    float M = -INFINITY;
    #pragma unroll
    for (int i = 0; i < 8; i++) {
        v[i] = v[i]*0.25f + mg[tid + i*256]*(-1e10f);
        M = fmaxf(M, v[i]);
    }
    #pragma unroll
    for (int off = 1; off < 64; off <<= 1) M = fmaxf(M, __shfl_xor(M, off, 64));
    const int wv = tid >> 6, lane = tid & 63;
    if (lane == 0) redm[wv] = M;
    __syncthreads();
    M = fmaxf(fmaxf(redm[0], redm[1]), fmaxf(redm[2], redm[3]));
    float S = 0.f;
    #pragma unroll
    for (int i = 0; i < 8; i++) { v[i] = __expf(v[i] - M); S += v[i]; }
    #pragma unroll
    for (int off = 1; off < 64; off <<= 1) S += __shfl_xor(S, off, 64);
    if (lane == 0) reds[wv] = S;
    __syncthreads();
    const float invS = 1.f / (reds[0] + reds[1] + reds[2] + reds[3]);
    #pragma unroll
    for (int i = 0; i < 8; i++) outh[(size_t)b*T + tid + i*256] = v[i]*invS;
}

// ---------------- K4: attn @ Wo^T + bo + x, LayerNorm(g1,be1) -> h ---------
__global__ __launch_bounds__(256) void k_proj_ln(
        const float* __restrict__ attnb, const float* __restrict__ x,
        const float* __restrict__ Wo, const float* __restrict__ bo,
        const float* __restrict__ g1, const float* __restrict__ be1,
        float* __restrict__ hb) {
    __shared__ float as_[16][D];
    const int tid = threadIdx.x;
    const size_t row0 = (size_t)blockIdx.x * 16;
    {
        const float4* ag = (const float4*)(attnb + row0*D);
        float4* s4 = (float4*)&as_[0][0];
        #pragma unroll
        for (int i = 0; i < 4; i++) s4[tid + i*256] = ag[tid + i*256];
    }
    __syncthreads();
    float acc[16];
    #pragma unroll
    for (int r = 0; r < 16; r++) acc[r] = 0.f;
    const float4* wp = (const float4*)(Wo + (size_t)tid * D);
    for (int d4 = 0; d4 < D/4; d4++) {
        float4 w = wp[d4];
        #pragma unroll
        for (int r = 0; r < 16; r++)
            acc[r] += dot4(w, *(const float4*)&as_[r][d4*4]);
    }
    const float bv = bo[tid];
    __syncthreads();
    #pragma unroll
    for (int r = 0; r < 16; r++)
        as_[r][tid] = acc[r] + bv + x[(row0 + r)*D + tid];
    __syncthreads();
    const int wv = tid >> 6, lane = tid & 63;
    float gvv[4], bvv[4];
    #pragma unroll
    for (int s2 = 0; s2 < 4; s2++) { gvv[s2] = g1[lane + 64*s2]; bvv[s2] = be1[lane + 64*s2]; }
    #pragma unroll
    for (int rr = 0; rr < 4; rr++) {
        const int r = wv*4 + rr;
        float x0 = as_[r][lane],     x1 = as_[r][lane+64];
        float x2 = as_[r][lane+128], x3 = as_[r][lane+192];
        float sum = x0+x1+x2+x3;
        float ssq = x0*x0 + x1*x1 + x2*x2 + x3*x3;
        #pragma unroll
        for (int off = 1; off < 64; off <<= 1) {
            sum += __shfl_xor(sum, off, 64);
            ssq += __shfl_xor(ssq, off, 64);
        }
        const float mu = sum * (1.f/256.f);
        const float rs = rsqrtf(ssq*(1.f/256.f) - mu*mu + 1e-5f);
        float* hp = hb + (row0 + r)*D;
        hp[lane]     = (x0 - mu)*rs*gvv[0] + bvv[0];
        hp[lane+64]  = (x1 - mu)*rs*gvv[1] + bvv[1];
        hp[lane+128] = (x2 - mu)*rs*gvv[2] + bvv[2];
        hp[lane+192] = (x3 - mu)*rs*gvv[3] + bvv[3];
    }
}

// ---------------- K5: fused FFN (relu(h@W1^T+b1)@W2^T+b2) + res + LN2 ------
__global__ __launch_bounds__(256) void k_ffn_ln(
        const float* __restrict__ hb, const float* __restrict__ W1,
        const float* __restrict__ b1, const float* __restrict__ W2,
        const float* __restrict__ b2, const float* __restrict__ g2,
        const float* __restrict__ be2, float* __restrict__ out) {
    __shared__ float hs[16][D];
    __shared__ float ms[16][FF];
    const int tid = threadIdx.x;
    const size_t row0 = (size_t)blockIdx.x * 16;
    {
        const float4* hg = (const float4*)(hb + row0*D);
        float4* s4 = (float4*)&hs[0][0];
        #pragma unroll
        for (int i = 0; i < 4; i++) s4[tid + i*256] = hg[tid + i*256];
    }
    __syncthreads();
    float a[4][16];
    #pragma unroll
    for (int c = 0; c < 4; c++) {
        #pragma unroll
        for (int r = 0; r < 16; r++) a[c][r] = 0.f;
    }
    {
        const float4* w1p0 = (const float4*)(W1 + (size_t)(tid)       * D);
        const float4* w1p1 = (const float4*)(W1 + (size_t)(tid + 256) * D);
        const float4* w1p2 = (const float4*)(W1 + (size_t)(tid + 512) * D);
        const float4* w1p3 = (const float4*)(W1 + (size_t)(tid + 768) * D);
        for (int d4 = 0; d4 < D/4; d4++) {
            float4 w0 = w1p0[d4], w1 = w1p1[d4], w2 = w1p2[d4], w3 = w1p3[d4];
            #pragma unroll
            for (int r = 0; r < 16; r++) {
                float4 hv = *(const float4*)&hs[r][d4*4];
                a[0][r] += dot4(w0, hv);
                a[1][r] += dot4(w1, hv);
                a[2][r] += dot4(w2, hv);
                a[3][r] += dot4(w3, hv);
            }
        }
    }
    #pragma unroll
    for (int c = 0; c < 4; c++) {
        const float bb = b1[tid + 256*c];
        #pragma unroll
        for (int r = 0; r < 16; r++)
            ms[r][tid + 256*c] = fmaxf(a[c][r] + bb, 0.f);
    }
    __syncthreads();
    float acc[16];
    #pragma unroll
    for (int r = 0; r < 16; r++) acc[r] = 0.f;
    const float4* w2p = (const float4*)(W2 + (size_t)tid * FF);
    for (int k4 = 0; k4 < FF/4; k4++) {
        float4 w = w2p[k4];
        #pragma unroll
        for (int r = 0; r < 16; r++)
            acc[r] += dot4(w, *(const float4*)&ms[r][k4*4]);
    }
    const float bb = b2[tid];
    __syncthreads();                 // done reading ms; reuse as val buffer
    float* vs = &ms[0][0];
    #pragma unroll
    for (int r = 0; r < 16; r++)
        vs[r*D + tid] = acc[r] + bb + hs[r][tid];
    __syncthreads();
    const int wv = tid >> 6, lane = tid & 63;
    float gvv[4], bvv[4];
    #pragma unroll
    for (int s2 = 0; s2 < 4; s2++) { gvv[s2] = g2[lane + 64*s2]; bvv[s2] = be2[lane + 64*s2]; }
    #pragma unroll
    for (int rr = 0; rr < 4; rr++) {
        const int r = wv*4 + rr;
        float x0 = vs[r*D + lane],     x1 = vs[r*D + lane+64];
        float x2 = vs[r*D + lane+128], x3 = vs[r*D + lane+192];
        float sum = x0+x1+x2+x3;
        float ssq = x0*x0 + x1*x1 + x2*x2 + x3*x3;
        #pragma unroll
        for (int off = 1; off < 64; off <<= 1) {
            sum += __shfl_xor(sum, off, 64);
            ssq += __shfl_xor(ssq, off, 64);
        }
        const float mu = sum * (1.f/256.f);
        const float rs = rsqrtf(ssq*(1.f/256.f) - mu*mu + 1e-5f);
        float* op = out + (row0 + r)*D;
        op[lane]     = (x0 - mu)*rs*gvv[0] + bvv[0];
        op[lane+64]  = (x1 - mu)*rs*gvv[1] + bvv[1];
        op[lane+128] = (x2 - mu)*rs*gvv[2] + bvv[2];
        op[lane+192] = (x3 - mu)*rs*gvv[3] + bvv[3];
    }
}

} // namespace

extern "C" void kernel_launch(void* const* d_in, const int* in_sizes, int n_in,
                              void* d_out, int out_size, void* d_ws, size_t ws_size,
                              hipStream_t stream) {
    (void)in_sizes; (void)n_in; (void)out_size; (void)ws_size;
    const float* x    = (const float*)d_in[0];
    const float* mask = (const float*)d_in[1];
    const float* Wqkv = (const float*)d_in[2];
    const float* bqkv = (const float*)d_in[3];
    const float* Wo   = (const float*)d_in[4];
    const float* bo   = (const float*)d_in[5];
    const float* W1   = (const float*)d_in[6];
    const float* b1   = (const float*)d_in[7];
    const float* W2   = (const float*)d_in[8];
    const float* b2   = (const float*)d_in[9];
    const float* g1   = (const float*)d_in[10];
    const float* be1  = (const float*)d_in[11];
    const float* g2   = (const float*)d_in[12];
    const float* be2  = (const float*)d_in[13];

    float* out = (float*)d_out;
    float* ws  = (float*)d_ws;
    const size_t BTD = (size_t)B * T * D;   // 4,194,304
    float* qb   = ws;
    float* kb   = ws + BTD;
    float* vb   = ws + 2*BTD;
    float* attn = ws + 3*BTD;
    float* hb   = ws + 4*BTD;
    float* part = ws + 5*BTD;               // B*256*T == BTD floats
    float* outh = out + BTD;

    k_qkv   <<<dim3(B*T/16),      256, 0, stream>>>(x, Wqkv, bqkv, qb, kb, vb);
    k_flash <<<dim3(T/32, H, B),  256, 0, stream>>>(qb, kb, vb, mask, attn, part);
    k_halt  <<<dim3(B),           256, 0, stream>>>(part, mask, outh);
    k_proj_ln<<<dim3(B*T/16),     256, 0, stream>>>(attn, x, Wo, bo, g1, be1, hb);
    k_ffn_ln<<<dim3(B*T/16),      256, 0, stream>>>(hb, W1, b1, W2, b2, g2, be2, out);
}

// Round 3
// 1060.403 us; speedup vs baseline: 1.8389x; 1.8389x over previous
//
#include <hip/hip_runtime.h>
#include <hip/hip_bf16.h>
#include <math.h>

namespace {

constexpr int B = 8, T = 2048, D = 256, H = 4, HD = 64, FF = 1024;

typedef __attribute__((ext_vector_type(8))) short short8;
typedef __attribute__((ext_vector_type(4))) float f32x4;

__device__ __forceinline__ float dot4(float4 a, float4 b) {
    return a.x*b.x + a.y*b.y + a.z*b.z + a.w*b.w;
}
__device__ __forceinline__ short f2bf(float f) {
    __hip_bfloat16 h = __float2bfloat16(f);
    return *reinterpret_cast<short*>(&h);
}

// ---------------- K1: qkv GEMM (fp32 VALU) -> bf16 q,k (bh,t,hd) + vT (bh,hd,t)
__global__ __launch_bounds__(256) void k_qkv(
        const float* __restrict__ x, const float* __restrict__ Wqkv,
        const float* __restrict__ bqkv,
        short* __restrict__ qb, short* __restrict__ kb, short* __restrict__ vtb) {
    __shared__ float xs[16][D];
    const int tid = threadIdx.x;
    const size_t row0 = (size_t)blockIdx.x * 16;
    {
        const float4* xg = (const float4*)(x + row0 * D);
        float4* s4 = (float4*)&xs[0][0];
        #pragma unroll
        for (int i = 0; i < 4; i++) s4[tid + i*256] = xg[tid + i*256];
    }
    __syncthreads();
    float a0[16], a1[16], a2[16];
    #pragma unroll
    for (int r = 0; r < 16; r++) { a0[r]=0.f; a1[r]=0.f; a2[r]=0.f; }
    const float4* w0p = (const float4*)(Wqkv + (size_t)tid * D);
    const float4* w1p = (const float4*)(Wqkv + (size_t)(tid+256) * D);
    const float4* w2p = (const float4*)(Wqkv + (size_t)(tid+512) * D);
    for (int d4 = 0; d4 < D/4; d4++) {
        float4 w0 = w0p[d4], w1 = w1p[d4], w2 = w2p[d4];
        #pragma unroll
        for (int r = 0; r < 16; r++) {
            float4 xv = *(const float4*)&xs[r][d4*4];
            a0[r] += dot4(w0, xv);
            a1[r] += dot4(w1, xv);
            a2[r] += dot4(w2, xv);
        }
    }
    const float bq = bqkv[tid], bk2 = bqkv[tid+256], bv = bqkv[tid+512];
    const int b = (int)(row0 >> 11);
    const int t0 = (int)(row0 & (size_t)(T-1));
    const int h = tid >> 6, d = tid & 63;
    const size_t qkbase = ((size_t)(b*H + h) * T + t0) * HD + d;
    #pragma unroll
    for (int r = 0; r < 16; r++) {
        qb[qkbase + (size_t)r*HD] = f2bf(a0[r] + bq);
        kb[qkbase + (size_t)r*HD] = f2bf(a1[r] + bk2);
    }
    short8 v0, v1;
    #pragma unroll
    for (int r = 0; r < 8; r++) v0[r] = f2bf(a2[r] + bv);
    #pragma unroll
    for (int r = 0; r < 8; r++) v1[r] = f2bf(a2[8+r] + bv);
    short* vp = vtb + ((size_t)(b*H + h) * HD + d) * T + t0;
    *(short8*)vp = v0;
    *(short8*)(vp + 8) = v1;
}

// ---------------- K2: MFMA flash attention + column-sum partials -----------
// block = 4 waves x 16 q-rows = 64 queries. grid (T/64, H, B).
// mfma_f32_16x16x32_bf16: A[l&15][8*(l>>4)+i], B[8*(l>>4)+i][l&15],
// D: row=(l>>4)*4+reg, col=l&15.
__global__ __launch_bounds__(256) void k_flash(
        const short* __restrict__ qb, const short* __restrict__ kb,
        const short* __restrict__ vtb, const float* __restrict__ mask,
        float* __restrict__ attnb, float* __restrict__ part) {
    __shared__ short Ks[64][72];      // [key][hd], stride 72 bf16
    __shared__ short Vt[64][72];      // [d][key]
    __shared__ short Ps[4][64][18];   // per-wave P^T [key][q], pad 2
    __shared__ float msk[64];
    __shared__ float colacc[4][64];

    const int tid = threadIdx.x;
    const int w = tid >> 6, lane = tid & 63;
    const int qr = lane & 15, g = lane >> 4;
    const int qt = blockIdx.x, h = blockIdx.y, b = blockIdx.z;
    const int bh = b*H + h;
    const int q0 = qt*64 + w*16;

    const short* qg = qb + ((size_t)bh * T + q0) * HD;
    const short8 qf0 = *(const short8*)(qg + qr*HD + g*8);
    const short8 qf1 = *(const short8*)(qg + qr*HD + 32 + g*8);

    const short* kg0 = kb + (size_t)bh * T * HD;
    const short* vg0 = vtb + (size_t)bh * HD * T;
    const float* mg  = mask + (size_t)b * T;
    const int skey = tid >> 2, sc = tid & 3;

    float mrun[4], lrun[4];
    f32x4 oa[4];
    #pragma unroll
    for (int i = 0; i < 4; i++) {
        mrun[i] = -3e38f; lrun[i] = 0.f;
        oa[i] = (f32x4){0.f, 0.f, 0.f, 0.f};
    }

    for (int kt = 0; kt < T/64; kt++) {
        __syncthreads();
        {
            const short* kg = kg0 + (size_t)(kt*64) * HD;
            *(short8*)&Ks[skey][sc*8]      = *(const short8*)(kg + skey*HD + sc*8);
            *(short8*)&Ks[skey][sc*8 + 32] = *(const short8*)(kg + skey*HD + sc*8 + 32);
            const short* vg = vg0 + kt*64;
            *(short8*)&Vt[skey][sc*8]      = *(const short8*)(vg + (size_t)skey*T + sc*8);
            *(short8*)&Vt[skey][sc*8 + 32] = *(const short8*)(vg + (size_t)skey*T + sc*8 + 32);
            if (tid < 64) msk[tid] = mg[kt*64 + tid];
        }
        __syncthreads();

        f32x4 sa[4];
        #pragma unroll
        for (int t4 = 0; t4 < 4; t4++) {
            sa[t4] = (f32x4){0.f, 0.f, 0.f, 0.f};
            short8 kf0 = *(const short8*)&Ks[t4*16 + qr][g*8];
            short8 kf1 = *(const short8*)&Ks[t4*16 + qr][g*8 + 32];
            sa[t4] = __builtin_amdgcn_mfma_f32_16x16x32_bf16(qf0, kf0, sa[t4], 0, 0, 0);
            sa[t4] = __builtin_amdgcn_mfma_f32_16x16x32_bf16(qf1, kf1, sa[t4], 0, 0, 0);
        }
        float sv[4][4], tmr[4];
        #pragma unroll
        for (int r = 0; r < 4; r++) tmr[r] = -3e38f;
        #pragma unroll
        for (int t4 = 0; t4 < 4; t4++) {
            const float mv = msk[t4*16 + qr];
            const bool dead = mv > 0.5f;
            #pragma unroll
            for (int r = 0; r < 4; r++) {
                sv[t4][r] = dead ? -1e9f : sa[t4][r]*0.125f;
                tmr[r] = fmaxf(tmr[r], sv[t4][r]);
            }
        }
        #pragma unroll
        for (int r = 0; r < 4; r++) {
            tmr[r] = fmaxf(tmr[r], __shfl_xor(tmr[r], 1, 64));
            tmr[r] = fmaxf(tmr[r], __shfl_xor(tmr[r], 2, 64));
            tmr[r] = fmaxf(tmr[r], __shfl_xor(tmr[r], 4, 64));
            tmr[r] = fmaxf(tmr[r], __shfl_xor(tmr[r], 8, 64));
        }
        float corr[4], ts[4], pv[4][4];
        #pragma unroll
        for (int r = 0; r < 4; r++) {
            const float mn = fmaxf(mrun[r], tmr[r]);
            corr[r] = __expf(mrun[r] - mn);
            mrun[r] = mn;
            ts[r] = 0.f;
        }
        #pragma unroll
        for (int t4 = 0; t4 < 4; t4++) {
            #pragma unroll
            for (int r = 0; r < 4; r++) {
                pv[t4][r] = __expf(sv[t4][r] - mrun[r]);
                ts[r] += pv[t4][r];
            }
        }
        #pragma unroll
        for (int r = 0; r < 4; r++) {
            ts[r] += __shfl_xor(ts[r], 1, 64);
            ts[r] += __shfl_xor(ts[r], 2, 64);
            ts[r] += __shfl_xor(ts[r], 4, 64);
            ts[r] += __shfl_xor(ts[r], 8, 64);
            lrun[r] = lrun[r]*corr[r] + ts[r];
        }
        #pragma unroll
        for (int nt = 0; nt < 4; nt++)
            #pragma unroll
            for (int r = 0; r < 4; r++) oa[nt][r] *= corr[r];
        // P repack: P^T[key][q] bf16, wave-private. Plain short stores: the
        // reads below are plain short loads -> same type, no TBAA reordering
        // of this barrier-free wave-local RAW (the R2 NaN bug).
        #pragma unroll
        for (int t4 = 0; t4 < 4; t4++) {
            #pragma unroll
            for (int r = 0; r < 4; r++)
                Ps[w][t4*16 + qr][4*g + r] = f2bf(pv[t4][r]);
        }
        short8 pa0, pa1;
        #pragma unroll
        for (int j = 0; j < 8; j++) pa0[j] = Ps[w][g*8 + j][qr];
        #pragma unroll
        for (int j = 0; j < 8; j++) pa1[j] = Ps[w][32 + g*8 + j][qr];
        #pragma unroll
        for (int nt = 0; nt < 4; nt++) {
            short8 vf0 = *(const short8*)&Vt[nt*16 + qr][g*8];
            short8 vf1 = *(const short8*)&Vt[nt*16 + qr][g*8 + 32];
            oa[nt] = __builtin_amdgcn_mfma_f32_16x16x32_bf16(pa0, vf0, oa[nt], 0, 0, 0);
            oa[nt] = __builtin_amdgcn_mfma_f32_16x16x32_bf16(pa1, vf1, oa[nt], 0, 0, 0);
        }
    }
    float invl[4];
    #pragma unroll
    for (int r = 0; r < 4; r++) invl[r] = 1.f / lrun[r];
    #pragma unroll
    for (int nt = 0; nt < 4; nt++) {
        #pragma unroll
        for (int r = 0; r < 4; r++) {
            const int t = q0 + 4*g + r;
            attnb[((size_t)b*T + t)*D + h*HD + nt*16 + qr] = oa[nt][r]*invl[r];
        }
    }
    // ---- second pass: column sums of normalized weights ----
    for (int kt = 0; kt < T/64; kt++) {
        __syncthreads();
        {
            const short* kg = kg0 + (size_t)(kt*64) * HD;
            *(short8*)&Ks[skey][sc*8]      = *(const short8*)(kg + skey*HD + sc*8);
            *(short8*)&Ks[skey][sc*8 + 32] = *(const short8*)(kg + skey*HD + sc*8 + 32);
            if (tid < 64) msk[tid] = mg[kt*64 + tid];
        }
        __syncthreads();
        float cs[4];
        #pragma unroll
        for (int t4 = 0; t4 < 4; t4++) {
            f32x4 sa = (f32x4){0.f, 0.f, 0.f, 0.f};
            short8 kf0 = *(const short8*)&Ks[t4*16 + qr][g*8];
            short8 kf1 = *(const short8*)&Ks[t4*16 + qr][g*8 + 32];
            sa = __builtin_amdgcn_mfma_f32_16x16x32_bf16(qf0, kf0, sa, 0, 0, 0);
            sa = __builtin_amdgcn_mfma_f32_16x16x32_bf16(qf1, kf1, sa, 0, 0, 0);
            const float mv = msk[t4*16 + qr];
            const bool dead = mv > 0.5f;
            float c = 0.f;
            #pragma unroll
            for (int r = 0; r < 4; r++) {
                float s = dead ? -1e9f : sa[r]*0.125f;
                c += __expf(s - mrun[r]) * invl[r];
            }
            cs[t4] = c;
        }
        #pragma unroll
        for (int t4 = 0; t4 < 4; t4++) {
            cs[t4] += __shfl_xor(cs[t4], 16, 64);
            cs[t4] += __shfl_xor(cs[t4], 32, 64);
        }
        if (lane < 16) {
            #pragma unroll
            for (int t4 = 0; t4 < 4; t4++) colacc[w][t4*16 + lane] = cs[t4];
        }
        __syncthreads();
        if (tid < 64)
            part[((size_t)bh*32 + qt)*T + kt*64 + tid] =
                colacc[0][tid] + colacc[1][tid] + colacc[2][tid] + colacc[3][tid];
    }
}

// ---------------- K3: halting = softmax(colsum/H + mask*(-1e10)) -----------
__global__ __launch_bounds__(256) void k_halt(
        const float* __restrict__ part, const float* __restrict__ mask,
        float* __restrict__ outh) {
    __shared__ float redm[4], reds[4];
    const int b = blockIdx.x, tid = threadIdx.x;
    float v[8];
    #pragma unroll
    for (int i = 0; i < 8; i++) v[i] = 0.f;
    const float* pb = part + (size_t)b * 128 * T;
    for (int p = 0; p < 128; p++) {
        const float* pp = pb + (size_t)p * T;
        #pragma unroll
        for (int i = 0; i < 8; i++) v[i] += pp[tid + i*256];
    }
    const float* mg = mask + (size_t)b * T;
    float M = -3e38f;
    #pragma unroll
    for (int i = 0; i < 8; i++) {
        v[i] = v[i]*0.25f + mg[tid + i*256]*(-1e10f);
        M = fmaxf(M, v[i]);
    }
    #pragma unroll
    for (int off = 1; off < 64; off <<= 1) M = fmaxf(M, __shfl_xor(M, off, 64));
    const int wv = tid >> 6, lane = tid & 63;
    if (lane == 0) redm[wv] = M;
    __syncthreads();
    M = fmaxf(fmaxf(redm[0], redm[1]), fmaxf(redm[2], redm[3]));
    float S = 0.f;
    #pragma unroll
    for (int i = 0; i < 8; i++) { v[i] = __expf(v[i] - M); S += v[i]; }
    #pragma unroll
    for (int off = 1; off < 64; off <<= 1) S += __shfl_xor(S, off, 64);
    if (lane == 0) reds[wv] = S;
    __syncthreads();
    const float invS = 1.f / (reds[0] + reds[1] + reds[2] + reds[3]);
    #pragma unroll
    for (int i = 0; i < 8; i++) outh[(size_t)b*T + tid + i*256] = v[i]*invS;
}

// ---------------- K4: attn @ Wo^T + bo + x, LayerNorm(g1,be1) -> h ---------
__global__ __launch_bounds__(256) void k_proj_ln(
        const float* __restrict__ attnb, const float* __restrict__ x,
        const float* __restrict__ Wo, const float* __restrict__ bo,
        const float* __restrict__ g1, const float* __restrict__ be1,
        float* __restrict__ hb) {
    __shared__ float as_[16][D];
    const int tid = threadIdx.x;
    const size_t row0 = (size_t)blockIdx.x * 16;
    {
        const float4* ag = (const float4*)(attnb + row0*D);
        float4* s4 = (float4*)&as_[0][0];
        #pragma unroll
        for (int i = 0; i < 4; i++) s4[tid + i*256] = ag[tid + i*256];
    }
    __syncthreads();
    float acc[16];
    #pragma unroll
    for (int r = 0; r < 16; r++) acc[r] = 0.f;
    const float4* wp = (const float4*)(Wo + (size_t)tid * D);
    for (int d4 = 0; d4 < D/4; d4++) {
        float4 w = wp[d4];
        #pragma unroll
        for (int r = 0; r < 16; r++)
            acc[r] += dot4(w, *(const float4*)&as_[r][d4*4]);
    }
    const float bv = bo[tid];
    __syncthreads();
    #pragma unroll
    for (int r = 0; r < 16; r++)
        as_[r][tid] = acc[r] + bv + x[(row0 + r)*D + tid];
    __syncthreads();
    const int wv = tid >> 6, lane = tid & 63;
    float gvv[4], bvv[4];
    #pragma unroll
    for (int s2 = 0; s2 < 4; s2++) { gvv[s2] = g1[lane + 64*s2]; bvv[s2] = be1[lane + 64*s2]; }
    #pragma unroll
    for (int rr = 0; rr < 4; rr++) {
        const int r = wv*4 + rr;
        float x0 = as_[r][lane],     x1 = as_[r][lane+64];
        float x2 = as_[r][lane+128], x3 = as_[r][lane+192];
        float sum = x0+x1+x2+x3;
        float ssq = x0*x0 + x1*x1 + x2*x2 + x3*x3;
        #pragma unroll
        for (int off = 1; off < 64; off <<= 1) {
            sum += __shfl_xor(sum, off, 64);
            ssq += __shfl_xor(ssq, off, 64);
        }
        const float mu = sum * (1.f/256.f);
        const float rs = rsqrtf(ssq*(1.f/256.f) - mu*mu + 1e-5f);
        float* hp = hb + (row0 + r)*D;
        hp[lane]     = (x0 - mu)*rs*gvv[0] + bvv[0];
        hp[lane+64]  = (x1 - mu)*rs*gvv[1] + bvv[1];
        hp[lane+128] = (x2 - mu)*rs*gvv[2] + bvv[2];
        hp[lane+192] = (x3 - mu)*rs*gvv[3] + bvv[3];
    }
}

// ---------------- K5: fused FFN + res + LN2 (48KB LDS, 2x512 chunks) -------
__global__ __launch_bounds__(256) void k_ffn_ln(
        const float* __restrict__ hb, const float* __restrict__ W1,
        const float* __restrict__ b1, const float* __restrict__ W2,
        const float* __restrict__ b2, const float* __restrict__ g2,
        const float* __restrict__ be2, float* __restrict__ out) {
    __shared__ float hs[16][D];
    __shared__ float ms[16][512];
    const int tid = threadIdx.x;
    const size_t row0 = (size_t)blockIdx.x * 16;
    {
        const float4* hg = (const float4*)(hb + row0*D);
        float4* s4 = (float4*)&hs[0][0];
        #pragma unroll
        for (int i = 0; i < 4; i++) s4[tid + i*256] = hg[tid + i*256];
    }
    __syncthreads();
    float acc[16];
    #pragma unroll
    for (int r = 0; r < 16; r++) acc[r] = 0.f;
    for (int c2 = 0; c2 < 2; c2++) {
        float a0[16], a1[16];
        #pragma unroll
        for (int r = 0; r < 16; r++) { a0[r] = 0.f; a1[r] = 0.f; }
        const float4* w1p0 = (const float4*)(W1 + (size_t)(c2*512 + tid) * D);
        const float4* w1p1 = (const float4*)(W1 + (size_t)(c2*512 + 256 + tid) * D);
        for (int d4 = 0; d4 < D/4; d4++) {
            float4 w0 = w1p0[d4], w1v = w1p1[d4];
            #pragma unroll
            for (int r = 0; r < 16; r++) {
                float4 hv = *(const float4*)&hs[r][d4*4];
                a0[r] += dot4(w0, hv);
                a1[r] += dot4(w1v, hv);
            }
        }
        __syncthreads();   // prior chunk's ms readers done
        const float bb0 = b1[c2*512 + tid], bb1 = b1[c2*512 + 256 + tid];
        #pragma unroll
        for (int r = 0; r < 16; r++) {
            ms[r][tid]       = fmaxf(a0[r] + bb0, 0.f);
            ms[r][tid + 256] = fmaxf(a1[r] + bb1, 0.f);
        }
        __syncthreads();
        const float4* w2p = (const float4*)(W2 + (size_t)tid * FF + c2*512);
        for (int k4 = 0; k4 < 128; k4++) {
            float4 wv = w2p[k4];
            #pragma unroll
            for (int r = 0; r < 16; r++)
                acc[r] += dot4(wv, *(const float4*)&ms[r][k4*4]);
        }
    }
    const float bb = b2[tid];
    __syncthreads();
    float* vs = &ms[0][0];
    #pragma unroll
    for (int r = 0; r < 16; r++)
        vs[r*D + tid] = acc[r] + bb + hs[r][tid];
    __syncthreads();
    const int wv = tid >> 6, lane = tid & 63;
    float gvv[4], bvv[4];
    #pragma unroll
    for (int s2 = 0; s2 < 4; s2++) { gvv[s2] = g2[lane + 64*s2]; bvv[s2] = be2[lane + 64*s2]; }
    #pragma unroll
    for (int rr = 0; rr < 4; rr++) {
        const int r = wv*4 + rr;
        float x0 = vs[r*D + lane],     x1 = vs[r*D + lane+64];
        float x2 = vs[r*D + lane+128], x3 = vs[r*D + lane+192];
        float sum = x0+x1+x2+x3;
        float ssq = x0*x0 + x1*x1 + x2*x2 + x3*x3;
        #pragma unroll
        for (int off = 1; off < 64; off <<= 1) {
            sum += __shfl_xor(sum, off, 64);
            ssq += __shfl_xor(ssq, off, 64);
        }
        const float mu = sum * (1.f/256.f);
        const float rs = rsqrtf(ssq*(1.f/256.f) - mu*mu + 1e-5f);
        float* op = out + (row0 + r)*D;
        op[lane]     = (x0 - mu)*rs*gvv[0] + bvv[0];
        op[lane+64]  = (x1 - mu)*rs*gvv[1] + bvv[1];
        op[lane+128] = (x2 - mu)*rs*gvv[2] + bvv[2];
        op[lane+192] = (x3 - mu)*rs*gvv[3] + bvv[3];
    }
}

} // namespace

extern "C" void kernel_launch(void* const* d_in, const int* in_sizes, int n_in,
                              void* d_out, int out_size, void* d_ws, size_t ws_size,
                              hipStream_t stream) {
    (void)in_sizes; (void)n_in; (void)out_size; (void)ws_size;
    const float* x    = (const float*)d_in[0];
    const float* mask = (const float*)d_in[1];
    const float* Wqkv = (const float*)d_in[2];
    const float* bqkv = (const float*)d_in[3];
    const float* Wo   = (const float*)d_in[4];
    const float* bo   = (const float*)d_in[5];
    const float* W1   = (const float*)d_in[6];
    const float* b1   = (const float*)d_in[7];
    const float* W2   = (const float*)d_in[8];
    const float* b2   = (const float*)d_in[9];
    const float* g1   = (const float*)d_in[10];
    const float* be1  = (const float*)d_in[11];
    const float* g2   = (const float*)d_in[12];
    const float* be2  = (const float*)d_in[13];

    float* out = (float*)d_out;
    float* ws  = (float*)d_ws;
    const size_t BTD = (size_t)B * T * D;          // 4,194,304
    const size_t NPART = (size_t)B * H * 32 * T;   // 2,097,152

    float* attn = ws;
    float* hb   = ws + BTD;
    float* part = ws + 2*BTD;
    short* qb16 = (short*)(ws + 2*BTD + NPART);
    short* kb16 = qb16 + BTD;
    short* vt16 = kb16 + BTD;
    float* outh = out + BTD;

    k_qkv    <<<dim3(B*T/16),     256, 0, stream>>>(x, Wqkv, bqkv, qb16, kb16, vt16);
    k_flash  <<<dim3(T/64, H, B), 256, 0, stream>>>(qb16, kb16, vt16, mask, attn, part);
    k_halt   <<<dim3(B),          256, 0, stream>>>(part, mask, outh);
    k_proj_ln<<<dim3(B*T/16),     256, 0, stream>>>(attn, x, Wo, bo, g1, be1, hb);
    k_ffn_ln <<<dim3(B*T/16),     256, 0, stream>>>(hb, W1, b1, W2, b2, g2, be2, out);
}

// Round 4
// 302.746 us; speedup vs baseline: 6.4408x; 3.5026x over previous
//
#include <hip/hip_runtime.h>
#include <hip/hip_bf16.h>
#include <math.h>

namespace {

constexpr int B = 8, T = 2048, D = 256, H = 4, HD = 64, FF = 1024;

typedef __attribute__((ext_vector_type(8))) short short8;
typedef __attribute__((ext_vector_type(4))) short s16x4;
typedef __attribute__((ext_vector_type(4))) float f32x4;

__device__ __forceinline__ short f2bf(float f) {
    __hip_bfloat16 h = __float2bfloat16(f);
    return *reinterpret_cast<short*>(&h);
}

// ---------------- K0: fp32 -> bf16 conversions (x + 4 weight matrices) -----
__global__ __launch_bounds__(256) void k_cvt(
        const float* __restrict__ x,  const float* __restrict__ wq,
        const float* __restrict__ wo, const float* __restrict__ w1,
        const float* __restrict__ w2,
        short* __restrict__ x16,  short* __restrict__ wq16,
        short* __restrict__ wo16, short* __restrict__ w116,
        short* __restrict__ w216) {
    const int N0 = 524288, N1 = 24576, N2 = 8192, N3 = 32768, N4 = 32768;
    const int total = N0 + N1 + N2 + N3 + N4;   // granules of 8 floats
    for (int i = blockIdx.x*256 + threadIdx.x; i < total; i += gridDim.x*256) {
        const float* s; short* d; int j = i;
        if (j < N0) { s = x; d = x16; }
        else { j -= N0;
            if (j < N1) { s = wq; d = wq16; }
            else { j -= N1;
                if (j < N2) { s = wo; d = wo16; }
                else { j -= N2;
                    if (j < N3) { s = w1; d = w116; }
                    else { j -= N3; s = w2; d = w216; }
                }
            }
        }
        float4 a = ((const float4*)s)[j*2], b2 = ((const float4*)s)[j*2+1];
        short8 o;
        o[0]=f2bf(a.x);  o[1]=f2bf(a.y);  o[2]=f2bf(a.z);  o[3]=f2bf(a.w);
        o[4]=f2bf(b2.x); o[5]=f2bf(b2.y); o[6]=f2bf(b2.z); o[7]=f2bf(b2.w);
        ((short8*)d)[j] = o;
    }
}

// ---------------- K_GEMM: C[M][N] = A[M][K] * W[N][K]^T, bf16 MFMA ---------
// 64x64 tile, BK=64, 4 waves in 2x2. LDS layout/frag reads copied from the
// proven k_flash pattern (stride-72 rows, [row][g*8 + 32*kk] b128 reads).
// MODE 0: qkv  (bias, scatter q/k rows, v transposed)   A=x16,   W=Wqkv16
// MODE 1: proj (bias, fp32 raw out)                     A=attn16,W=Wo16
// MODE 2: ffn1 (bias, relu, bf16 out [m][1024])         A=h16,   W=W116
// MODE 3: ffn2 (bias, fp32 raw out)                     A=mid16, W=W216
template<int MODE>
__global__ __launch_bounds__(256) void k_gemm(
        const short* __restrict__ A, const short* __restrict__ W,
        const float* __restrict__ bias, const int K,
        short* __restrict__ oq, short* __restrict__ ok, short* __restrict__ ov,
        float* __restrict__ of, short* __restrict__ o16) {
    __shared__ short As[64][72];
    __shared__ short Ws[64][72];
    __shared__ float Cs[64][68];
    const int tid = threadIdx.x;
    const int w = tid >> 6, lane = tid & 63;
    const int qr = lane & 15, g = lane >> 4;
    const int wm = w >> 1, wn = w & 1;
    const int m0 = blockIdx.x * 64;
    const int n0 = blockIdx.y * 64;
    const int srow = tid >> 2, scol = (tid & 3) * 8;
    const short* Ag = A + (size_t)(m0 + srow) * K + scol;
    const short* Wg = W + (size_t)(n0 + srow) * K + scol;

    f32x4 acc[2][2];
    #pragma unroll
    for (int i = 0; i < 2; i++)
        #pragma unroll
        for (int j = 0; j < 2; j++) acc[i][j] = (f32x4){0.f, 0.f, 0.f, 0.f};

    for (int k0 = 0; k0 < K; k0 += 64) {
        __syncthreads();
        *(short8*)&As[srow][scol]      = *(const short8*)(Ag + k0);
        *(short8*)&As[srow][scol + 32] = *(const short8*)(Ag + k0 + 32);
        *(short8*)&Ws[srow][scol]      = *(const short8*)(Wg + k0);
        *(short8*)&Ws[srow][scol + 32] = *(const short8*)(Wg + k0 + 32);
        __syncthreads();
        #pragma unroll
        for (int kk = 0; kk < 2; kk++) {
            short8 a0 = *(const short8*)&As[wm*32 + qr][g*8 + kk*32];
            short8 a1 = *(const short8*)&As[wm*32 + 16 + qr][g*8 + kk*32];
            short8 b0 = *(const short8*)&Ws[wn*32 + qr][g*8 + kk*32];
            short8 b1 = *(const short8*)&Ws[wn*32 + 16 + qr][g*8 + kk*32];
            acc[0][0] = __builtin_amdgcn_mfma_f32_16x16x32_bf16(a0, b0, acc[0][0], 0, 0, 0);
            acc[0][1] = __builtin_amdgcn_mfma_f32_16x16x32_bf16(a0, b1, acc[0][1], 0, 0, 0);
            acc[1][0] = __builtin_amdgcn_mfma_f32_16x16x32_bf16(a1, b0, acc[1][0], 0, 0, 0);
            acc[1][1] = __builtin_amdgcn_mfma_f32_16x16x32_bf16(a1, b1, acc[1][1], 0, 0, 0);
        }
    }

    const int b = m0 >> 11;
    const int tl0 = m0 & (T - 1);

    if (MODE == 0 && blockIdx.y >= 8) {
        // v tiles: write transposed vT[bh][d][t], 4 consecutive t per frag reg
        const int h = (int)blockIdx.y - 8;
        #pragma unroll
        for (int fm = 0; fm < 2; fm++) {
            const int tbase = tl0 + wm*32 + fm*16 + g*4;
            #pragma unroll
            for (int fn = 0; fn < 2; fn++) {
                const int d = wn*32 + fn*16 + qr;
                const float bv = bias[n0 + d];
                s16x4 pk;
                #pragma unroll
                for (int r = 0; r < 4; r++) pk[r] = f2bf(acc[fm][fn][r] + bv);
                *(s16x4*)&ov[((size_t)(b*H + h)*HD + d)*T + tbase] = pk;
            }
        }
        return;
    }

    // repack fragments -> Cs, then vectorized row writes
    #pragma unroll
    for (int fm = 0; fm < 2; fm++)
        #pragma unroll
        for (int fn = 0; fn < 2; fn++)
            #pragma unroll
            for (int r = 0; r < 4; r++)
                Cs[wm*32 + fm*16 + g*4 + r][wn*32 + fn*16 + qr] = acc[fm][fn][r];
    __syncthreads();
    const int row = tid >> 2, c0 = (tid & 3) * 16;
    float vals[16];
    #pragma unroll
    for (int j = 0; j < 16; j++) vals[j] = Cs[row][c0 + j] + bias[n0 + c0 + j];

    if (MODE == 0) {
        const int by = blockIdx.y;
        short* dst = (by < 4) ? oq : ok;
        const int h = by & 3;
        short8 s0, s1;
        #pragma unroll
        for (int j = 0; j < 8; j++) { s0[j] = f2bf(vals[j]); s1[j] = f2bf(vals[8+j]); }
        short* p = dst + ((size_t)(b*H + h)*T + tl0 + row)*HD + c0;
        *(short8*)p = s0;
        *(short8*)(p + 8) = s1;
    } else if (MODE == 1 || MODE == 3) {
        float* p = of + (size_t)(m0 + row)*256 + n0 + c0;
        #pragma unroll
        for (int jj = 0; jj < 4; jj++) *(float4*)(p + jj*4) = *(float4*)&vals[jj*4];
    } else {  // MODE 2: relu -> bf16 mid [m][1024]
        short8 s0, s1;
        #pragma unroll
        for (int j = 0; j < 8; j++) {
            s0[j] = f2bf(fmaxf(vals[j], 0.f));
            s1[j] = f2bf(fmaxf(vals[8+j], 0.f));
        }
        short* p = o16 + (size_t)(m0 + row)*1024 + n0 + c0;
        *(short8*)p = s0;
        *(short8*)(p + 8) = s1;
    }
}

// ---------------- K2: MFMA flash attention + column-sum partials -----------
__global__ __launch_bounds__(256) void k_flash(
        const short* __restrict__ qb, const short* __restrict__ kb,
        const short* __restrict__ vtb, const float* __restrict__ mask,
        short* __restrict__ attnb, float* __restrict__ part) {
    __shared__ short Ks[64][72];
    __shared__ short Vt[64][72];
    __shared__ short Ps[4][64][18];
    __shared__ float msk[64];
    __shared__ float colacc[4][64];

    const int tid = threadIdx.x;
    const int w = tid >> 6, lane = tid & 63;
    const int qr = lane & 15, g = lane >> 4;
    const int qt = blockIdx.x, h = blockIdx.y, b = blockIdx.z;
    const int bh = b*H + h;
    const int q0 = qt*64 + w*16;

    const short* qg = qb + ((size_t)bh * T + q0) * HD;
    const short8 qf0 = *(const short8*)(qg + qr*HD + g*8);
    const short8 qf1 = *(const short8*)(qg + qr*HD + 32 + g*8);

    const short* kg0 = kb + (size_t)bh * T * HD;
    const short* vg0 = vtb + (size_t)bh * HD * T;
    const float* mg  = mask + (size_t)b * T;
    const int skey = tid >> 2, sc = tid & 3;

    float mrun[4], lrun[4];
    f32x4 oa[4];
    #pragma unroll
    for (int i = 0; i < 4; i++) {
        mrun[i] = -3e38f; lrun[i] = 0.f;
        oa[i] = (f32x4){0.f, 0.f, 0.f, 0.f};
    }

    for (int kt = 0; kt < T/64; kt++) {
        __syncthreads();
        {
            const short* kg = kg0 + (size_t)(kt*64) * HD;
            *(short8*)&Ks[skey][sc*8]      = *(const short8*)(kg + skey*HD + sc*8);
            *(short8*)&Ks[skey][sc*8 + 32] = *(const short8*)(kg + skey*HD + sc*8 + 32);
            const short* vg = vg0 + kt*64;
            *(short8*)&Vt[skey][sc*8]      = *(const short8*)(vg + (size_t)skey*T + sc*8);
            *(short8*)&Vt[skey][sc*8 + 32] = *(const short8*)(vg + (size_t)skey*T + sc*8 + 32);
            if (tid < 64) msk[tid] = mg[kt*64 + tid];
        }
        __syncthreads();

        f32x4 sa[4];
        #pragma unroll
        for (int t4 = 0; t4 < 4; t4++) {
            sa[t4] = (f32x4){0.f, 0.f, 0.f, 0.f};
            short8 kf0 = *(const short8*)&Ks[t4*16 + qr][g*8];
            short8 kf1 = *(const short8*)&Ks[t4*16 + qr][g*8 + 32];
            sa[t4] = __builtin_amdgcn_mfma_f32_16x16x32_bf16(qf0, kf0, sa[t4], 0, 0, 0);
            sa[t4] = __builtin_amdgcn_mfma_f32_16x16x32_bf16(qf1, kf1, sa[t4], 0, 0, 0);
        }
        float sv[4][4], tmr[4];
        #pragma unroll
        for (int r = 0; r < 4; r++) tmr[r] = -3e38f;
        #pragma unroll
        for (int t4 = 0; t4 < 4; t4++) {
            const float mv = msk[t4*16 + qr];
            const bool dead = mv > 0.5f;
            #pragma unroll
            for (int r = 0; r < 4; r++) {
                sv[t4][r] = dead ? -1e9f : sa[t4][r]*0.125f;
                tmr[r] = fmaxf(tmr[r], sv[t4][r]);
            }
        }
        #pragma unroll
        for (int r = 0; r < 4; r++) {
            tmr[r] = fmaxf(tmr[r], __shfl_xor(tmr[r], 1, 64));
            tmr[r] = fmaxf(tmr[r], __shfl_xor(tmr[r], 2, 64));
            tmr[r] = fmaxf(tmr[r], __shfl_xor(tmr[r], 4, 64));
            tmr[r] = fmaxf(tmr[r], __shfl_xor(tmr[r], 8, 64));
        }
        float corr[4], ts[4], pv[4][4];
        #pragma unroll
        for (int r = 0; r < 4; r++) {
            const float mn = fmaxf(mrun[r], tmr[r]);
            corr[r] = __expf(mrun[r] - mn);
            mrun[r] = mn;
            ts[r] = 0.f;
        }
        #pragma unroll
        for (int t4 = 0; t4 < 4; t4++) {
            #pragma unroll
            for (int r = 0; r < 4; r++) {
                pv[t4][r] = __expf(sv[t4][r] - mrun[r]);
                ts[r] += pv[t4][r];
            }
        }
        #pragma unroll
        for (int r = 0; r < 4; r++) {
            ts[r] += __shfl_xor(ts[r], 1, 64);
            ts[r] += __shfl_xor(ts[r], 2, 64);
            ts[r] += __shfl_xor(ts[r], 4, 64);
            ts[r] += __shfl_xor(ts[r], 8, 64);
            lrun[r] = lrun[r]*corr[r] + ts[r];
        }
        #pragma unroll
        for (int nt = 0; nt < 4; nt++)
            #pragma unroll
            for (int r = 0; r < 4; r++) oa[nt][r] *= corr[r];
        #pragma unroll
        for (int t4 = 0; t4 < 4; t4++) {
            #pragma unroll
            for (int r = 0; r < 4; r++)
                Ps[w][t4*16 + qr][4*g + r] = f2bf(pv[t4][r]);
        }
        short8 pa0, pa1;
        #pragma unroll
        for (int j = 0; j < 8; j++) pa0[j] = Ps[w][g*8 + j][qr];
        #pragma unroll
        for (int j = 0; j < 8; j++) pa1[j] = Ps[w][32 + g*8 + j][qr];
        #pragma unroll
        for (int nt = 0; nt < 4; nt++) {
            short8 vf0 = *(const short8*)&Vt[nt*16 + qr][g*8];
            short8 vf1 = *(const short8*)&Vt[nt*16 + qr][g*8 + 32];
            oa[nt] = __builtin_amdgcn_mfma_f32_16x16x32_bf16(pa0, vf0, oa[nt], 0, 0, 0);
            oa[nt] = __builtin_amdgcn_mfma_f32_16x16x32_bf16(pa1, vf1, oa[nt], 0, 0, 0);
        }
    }
    float invl[4];
    #pragma unroll
    for (int r = 0; r < 4; r++) invl[r] = 1.f / lrun[r];
    #pragma unroll
    for (int nt = 0; nt < 4; nt++) {
        #pragma unroll
        for (int r = 0; r < 4; r++) {
            const int t = q0 + 4*g + r;
            attnb[((size_t)b*T + t)*D + h*HD + nt*16 + qr] = f2bf(oa[nt][r]*invl[r]);
        }
    }
    // second pass: column sums of normalized weights
    for (int kt = 0; kt < T/64; kt++) {
        __syncthreads();
        {
            const short* kg = kg0 + (size_t)(kt*64) * HD;
            *(short8*)&Ks[skey][sc*8]      = *(const short8*)(kg + skey*HD + sc*8);
            *(short8*)&Ks[skey][sc*8 + 32] = *(const short8*)(kg + skey*HD + sc*8 + 32);
            if (tid < 64) msk[tid] = mg[kt*64 + tid];
        }
        __syncthreads();
        float cs[4];
        #pragma unroll
        for (int t4 = 0; t4 < 4; t4++) {
            f32x4 sa = (f32x4){0.f, 0.f, 0.f, 0.f};
            short8 kf0 = *(const short8*)&Ks[t4*16 + qr][g*8];
            short8 kf1 = *(const short8*)&Ks[t4*16 + qr][g*8 + 32];
            sa = __builtin_amdgcn_mfma_f32_16x16x32_bf16(qf0, kf0, sa, 0, 0, 0);
            sa = __builtin_amdgcn_mfma_f32_16x16x32_bf16(qf1, kf1, sa, 0, 0, 0);
            const float mv = msk[t4*16 + qr];
            const bool dead = mv > 0.5f;
            float c = 0.f;
            #pragma unroll
            for (int r = 0; r < 4; r++) {
                float s = dead ? -1e9f : sa[r]*0.125f;
                c += __expf(s - mrun[r]) * invl[r];
            }
            cs[t4] = c;
        }
        #pragma unroll
        for (int t4 = 0; t4 < 4; t4++) {
            cs[t4] += __shfl_xor(cs[t4], 16, 64);
            cs[t4] += __shfl_xor(cs[t4], 32, 64);
        }
        if (lane < 16) {
            #pragma unroll
            for (int t4 = 0; t4 < 4; t4++) colacc[w][t4*16 + lane] = cs[t4];
        }
        __syncthreads();
        if (tid < 64)
            part[((size_t)bh*32 + qt)*T + kt*64 + tid] =
                colacc[0][tid] + colacc[1][tid] + colacc[2][tid] + colacc[3][tid];
    }
}

// ---------------- K3: halting = softmax(colsum/H + mask*(-1e10)) -----------
__global__ __launch_bounds__(256) void k_halt(
        const float* __restrict__ part, const float* __restrict__ mask,
        float* __restrict__ outh) {
    __shared__ float redm[4], reds[4];
    const int b = blockIdx.x, tid = threadIdx.x;
    float v[8];
    #pragma unroll
    for (int i = 0; i < 8; i++) v[i] = 0.f;
    const float* pb = part + (size_t)b * 128 * T;
    for (int p = 0; p < 128; p++) {
        const float* pp = pb + (size_t)p * T;
        #pragma unroll
        for (int i = 0; i < 8; i++) v[i] += pp[tid + i*256];
    }
    const float* mg = mask + (size_t)b * T;
    float M = -3e38f;
    #pragma unroll
    for (int i = 0; i < 8; i++) {
        v[i] = v[i]*0.25f + mg[tid + i*256]*(-1e10f);
        M = fmaxf(M, v[i]);
    }
    #pragma unroll
    for (int off = 1; off < 64; off <<= 1) M = fmaxf(M, __shfl_xor(M, off, 64));
    const int wv = tid >> 6, lane = tid & 63;
    if (lane == 0) redm[wv] = M;
    __syncthreads();
    M = fmaxf(fmaxf(redm[0], redm[1]), fmaxf(redm[2], redm[3]));
    float S = 0.f;
    #pragma unroll
    for (int i = 0; i < 8; i++) { v[i] = __expf(v[i] - M); S += v[i]; }
    #pragma unroll
    for (int off = 1; off < 64; off <<= 1) S += __shfl_xor(S, off, 64);
    if (lane == 0) reds[wv] = S;
    __syncthreads();
    const float invS = 1.f / (reds[0] + reds[1] + reds[2] + reds[3]);
    #pragma unroll
    for (int i = 0; i < 8; i++) outh[(size_t)b*T + tid + i*256] = v[i]*invS;
}

// ---------------- K_LN: y = LN(a + bsrc)*g + be; optional bf16 copy --------
__global__ __launch_bounds__(256) void k_ln(
        const float* __restrict__ a, const float* __restrict__ bsrc,
        const float* __restrict__ g, const float* __restrict__ be,
        float* __restrict__ yf, short* __restrict__ y16) {
    __shared__ float s[16][D];
    const int tid = threadIdx.x;
    const size_t row0 = (size_t)blockIdx.x * 16;
    const float4* ag = (const float4*)(a + row0*D);
    const float4* bg = (const float4*)(bsrc + row0*D);
    #pragma unroll
    for (int i = 0; i < 4; i++) {
        float4 av = ag[tid + i*256], bv = bg[tid + i*256];
        float4 sv = {av.x+bv.x, av.y+bv.y, av.z+bv.z, av.w+bv.w};
        ((float4*)&s[0][0])[tid + i*256] = sv;
    }
    __syncthreads();
    const int wv = tid >> 6, lane = tid & 63;
    float gvv[4], bvv[4];
    #pragma unroll
    for (int s2 = 0; s2 < 4; s2++) { gvv[s2] = g[lane + 64*s2]; bvv[s2] = be[lane + 64*s2]; }
    #pragma unroll
    for (int rr = 0; rr < 4; rr++) {
        const int r = wv*4 + rr;
        float x0 = s[r][lane],     x1 = s[r][lane+64];
        float x2 = s[r][lane+128], x3 = s[r][lane+192];
        float sum = x0+x1+x2+x3;
        float ssq = x0*x0 + x1*x1 + x2*x2 + x3*x3;
        #pragma unroll
        for (int off = 1; off < 64; off <<= 1) {
            sum += __shfl_xor(sum, off, 64);
            ssq += __shfl_xor(ssq, off, 64);
        }
        const float mu = sum * (1.f/256.f);
        const float rs = rsqrtf(ssq*(1.f/256.f) - mu*mu + 1e-5f);
        float y0 = (x0 - mu)*rs*gvv[0] + bvv[0];
        float y1 = (x1 - mu)*rs*gvv[1] + bvv[1];
        float y2 = (x2 - mu)*rs*gvv[2] + bvv[2];
        float y3 = (x3 - mu)*rs*gvv[3] + bvv[3];
        float* yp = yf + (row0 + r)*D;
        yp[lane]     = y0;
        yp[lane+64]  = y1;
        yp[lane+128] = y2;
        yp[lane+192] = y3;
        if (y16) {
            short* hp = y16 + (row0 + r)*D;
            hp[lane]     = f2bf(y0);
            hp[lane+64]  = f2bf(y1);
            hp[lane+128] = f2bf(y2);
            hp[lane+192] = f2bf(y3);
        }
    }
}

} // namespace

extern "C" void kernel_launch(void* const* d_in, const int* in_sizes, int n_in,
                              void* d_out, int out_size, void* d_ws, size_t ws_size,
                              hipStream_t stream) {
    (void)in_sizes; (void)n_in; (void)out_size; (void)ws_size;
    const float* x    = (const float*)d_in[0];
    const float* mask = (const float*)d_in[1];
    const float* Wqkv = (const float*)d_in[2];
    const float* bqkv = (const float*)d_in[3];
    const float* Wo   = (const float*)d_in[4];
    const float* bo   = (const float*)d_in[5];
    const float* W1   = (const float*)d_in[6];
    const float* b1   = (const float*)d_in[7];
    const float* W2   = (const float*)d_in[8];
    const float* b2   = (const float*)d_in[9];
    const float* g1   = (const float*)d_in[10];
    const float* be1  = (const float*)d_in[11];
    const float* g2   = (const float*)d_in[12];
    const float* be2  = (const float*)d_in[13];

    float* out  = (float*)d_out;
    char*  wsb  = (char*)d_ws;
    const size_t MB = 1024*1024;

    // liveness-overlaid layout (82 MB total; >=100.6 MB proven available in R1)
    short* qb16   = (short*)(wsb + 0*MB);    // dead after flash
    short* kb16   = (short*)(wsb + 8*MB);    // dead after flash
    short* vt16   = (short*)(wsb + 16*MB);   // dead after flash
    short* x16    = (short*)(wsb + 24*MB);   // dead after gemm0
    short* attn16 = (short*)(wsb + 24*MB);   // written by flash, dead after proj
    float* part   = (float*)(wsb + 32*MB);   // dead after halt
    float* hb     = (float*)(wsb + 40*MB);   // live until ln2
    short* h16    = (short*)(wsb + 56*MB);   // dead after ffn1
    short* wq16   = (short*)(wsb + 64*MB);
    short* wo16   = (short*)(wsb + 64*MB + 393216);
    short* w116   = (short*)(wsb + 64*MB + 524288);
    short* w216   = (short*)(wsb + 64*MB + 1048576);
    float* po     = (float*)(wsb + 66*MB);   // dead after ln1
    float* fo     = (float*)(wsb + 66*MB);   // written by ffn2 (po dead)
    short* mid16  = (short*)(wsb + 0*MB);    // [0..32MB], overlays q/k/v/attn (all dead)
    float* outh   = out + (size_t)B*T*D;

    k_cvt    <<<dim3(1024),        256, 0, stream>>>(x, Wqkv, Wo, W1, W2,
                                                     x16, wq16, wo16, w116, w216);
    k_gemm<0><<<dim3(256, 12),     256, 0, stream>>>(x16, wq16, bqkv, 256,
                                                     qb16, kb16, vt16, nullptr, nullptr);
    k_flash  <<<dim3(T/64, H, B),  256, 0, stream>>>(qb16, kb16, vt16, mask, attn16, part);
    k_halt   <<<dim3(B),           256, 0, stream>>>(part, mask, outh);
    k_gemm<1><<<dim3(256, 4),      256, 0, stream>>>(attn16, wo16, bo, 256,
                                                     nullptr, nullptr, nullptr, po, nullptr);
    k_ln     <<<dim3(B*T/16),      256, 0, stream>>>(x, po, g1, be1, hb, h16);
    k_gemm<2><<<dim3(256, 16),     256, 0, stream>>>(h16, w116, b1, 256,
                                                     nullptr, nullptr, nullptr, nullptr, mid16);
    k_gemm<3><<<dim3(256, 4),      256, 0, stream>>>(mid16, w216, b2, 1024,
                                                     nullptr, nullptr, nullptr, fo, nullptr);
    k_ln     <<<dim3(B*T/16),      256, 0, stream>>>(hb, fo, g2, be2, out, nullptr);
}

// Round 5
// 241.320 us; speedup vs baseline: 8.0803x; 1.2545x over previous
//
#include <hip/hip_runtime.h>
#include <hip/hip_bf16.h>
#include <math.h>

namespace {

constexpr int B = 8, T = 2048, D = 256, H = 4, HD = 64, FF = 1024;
constexpr float QSCALE = 0.18033688f;   // 0.125 * log2(e)

typedef __attribute__((ext_vector_type(8))) short short8;
typedef __attribute__((ext_vector_type(4))) short s16x4;
typedef __attribute__((ext_vector_type(4))) float f32x4;

__device__ __forceinline__ float dot4(float4 a, float4 b) {
    return a.x*b.x + a.y*b.y + a.z*b.z + a.w*b.w;
}
__device__ __forceinline__ short f2bf(float f) {
    __hip_bfloat16 h = __float2bfloat16(f);
    return *reinterpret_cast<short*>(&h);
}
__device__ __forceinline__ float exp2a(float x) {
    float r; asm("v_exp_f32 %0, %1" : "=v"(r) : "v"(x)); return r;
}
__device__ __forceinline__ unsigned cvtpk(float lo, float hi) {
    unsigned r; asm("v_cvt_pk_bf16_f32 %0, %1, %2" : "=v"(r) : "v"(lo), "v"(hi)); return r;
}

// ---------------- K0: fp32 -> bf16 conversions (x + 4 weight matrices) -----
__global__ __launch_bounds__(256) void k_cvt(
        const float* __restrict__ x,  const float* __restrict__ wq,
        const float* __restrict__ wo, const float* __restrict__ w1,
        const float* __restrict__ w2,
        short* __restrict__ x16,  short* __restrict__ wq16,
        short* __restrict__ wo16, short* __restrict__ w116,
        short* __restrict__ w216) {
    const int N0 = 524288, N1 = 24576, N2 = 8192, N3 = 32768, N4 = 32768;
    const int total = N0 + N1 + N2 + N3 + N4;   // granules of 8 floats
    for (int i = blockIdx.x*256 + threadIdx.x; i < total; i += gridDim.x*256) {
        const float* s; short* d; int j = i;
        if (j < N0) { s = x; d = x16; }
        else { j -= N0;
            if (j < N1) { s = wq; d = wq16; }
            else { j -= N1;
                if (j < N2) { s = wo; d = wo16; }
                else { j -= N2;
                    if (j < N3) { s = w1; d = w116; }
                    else { j -= N3; s = w2; d = w216; }
                }
            }
        }
        float4 a = ((const float4*)s)[j*2], b2 = ((const float4*)s)[j*2+1];
        short8 o;
        o[0]=f2bf(a.x);  o[1]=f2bf(a.y);  o[2]=f2bf(a.z);  o[3]=f2bf(a.w);
        o[4]=f2bf(b2.x); o[5]=f2bf(b2.y); o[6]=f2bf(b2.z); o[7]=f2bf(b2.w);
        ((short8*)d)[j] = o;
    }
}

// ---------------- K_GEMM: C[M][N] = A[M][K] * W[N][K]^T, bf16 MFMA ---------
// MODE 0: qkv  (bias, scatter q/k rows [q pre-scaled], v transposed)
// MODE 1: proj (bias, fp32 raw out)
// MODE 2: ffn1 (bias, relu, bf16 out [m][1024])
// MODE 3: ffn2 (bias, fp32 raw out)
template<int MODE>
__global__ __launch_bounds__(256) void k_gemm(
        const short* __restrict__ A, const short* __restrict__ W,
        const float* __restrict__ bias, const int K,
        short* __restrict__ oq, short* __restrict__ ok, short* __restrict__ ov,
        float* __restrict__ of, short* __restrict__ o16) {
    __shared__ short As[64][72];
    __shared__ short Ws[64][72];
    __shared__ float Cs[64][68];
    const int tid = threadIdx.x;
    const int w = tid >> 6, lane = tid & 63;
    const int qr = lane & 15, g = lane >> 4;
    const int wm = w >> 1, wn = w & 1;
    const int m0 = blockIdx.x * 64;
    const int n0 = blockIdx.y * 64;
    const int srow = tid >> 2, scol = (tid & 3) * 8;
    const short* Ag = A + (size_t)(m0 + srow) * K + scol;
    const short* Wg = W + (size_t)(n0 + srow) * K + scol;

    f32x4 acc[2][2];
    #pragma unroll
    for (int i = 0; i < 2; i++)
        #pragma unroll
        for (int j = 0; j < 2; j++) acc[i][j] = (f32x4){0.f, 0.f, 0.f, 0.f};

    for (int k0 = 0; k0 < K; k0 += 64) {
        __syncthreads();
        *(short8*)&As[srow][scol]      = *(const short8*)(Ag + k0);
        *(short8*)&As[srow][scol + 32] = *(const short8*)(Ag + k0 + 32);
        *(short8*)&Ws[srow][scol]      = *(const short8*)(Wg + k0);
        *(short8*)&Ws[srow][scol + 32] = *(const short8*)(Wg + k0 + 32);
        __syncthreads();
        #pragma unroll
        for (int kk = 0; kk < 2; kk++) {
            short8 a0 = *(const short8*)&As[wm*32 + qr][g*8 + kk*32];
            short8 a1 = *(const short8*)&As[wm*32 + 16 + qr][g*8 + kk*32];
            short8 b0 = *(const short8*)&Ws[wn*32 + qr][g*8 + kk*32];
            short8 b1 = *(const short8*)&Ws[wn*32 + 16 + qr][g*8 + kk*32];
            acc[0][0] = __builtin_amdgcn_mfma_f32_16x16x32_bf16(a0, b0, acc[0][0], 0, 0, 0);
            acc[0][1] = __builtin_amdgcn_mfma_f32_16x16x32_bf16(a0, b1, acc[0][1], 0, 0, 0);
            acc[1][0] = __builtin_amdgcn_mfma_f32_16x16x32_bf16(a1, b0, acc[1][0], 0, 0, 0);
            acc[1][1] = __builtin_amdgcn_mfma_f32_16x16x32_bf16(a1, b1, acc[1][1], 0, 0, 0);
        }
    }

    const int b = m0 >> 11;
    const int tl0 = m0 & (T - 1);

    if (MODE == 0 && blockIdx.y >= 8) {
        const int h = (int)blockIdx.y - 8;
        #pragma unroll
        for (int fm = 0; fm < 2; fm++) {
            const int tbase = tl0 + wm*32 + fm*16 + g*4;
            #pragma unroll
            for (int fn = 0; fn < 2; fn++) {
                const int d = wn*32 + fn*16 + qr;
                const float bv = bias[n0 + d];
                s16x4 pk;
                #pragma unroll
                for (int r = 0; r < 4; r++) pk[r] = f2bf(acc[fm][fn][r] + bv);
                *(s16x4*)&ov[((size_t)(b*H + h)*HD + d)*T + tbase] = pk;
            }
        }
        return;
    }

    #pragma unroll
    for (int fm = 0; fm < 2; fm++)
        #pragma unroll
        for (int fn = 0; fn < 2; fn++)
            #pragma unroll
            for (int r = 0; r < 4; r++)
                Cs[wm*32 + fm*16 + g*4 + r][wn*32 + fn*16 + qr] = acc[fm][fn][r];
    __syncthreads();
    const int row = tid >> 2, c0 = (tid & 3) * 16;
    float vals[16];
    #pragma unroll
    for (int j = 0; j < 16; j++) vals[j] = Cs[row][c0 + j] + bias[n0 + c0 + j];

    if (MODE == 0) {
        const int by = blockIdx.y;
        short* dst = (by < 4) ? oq : ok;
        const float qs = (by < 4) ? QSCALE : 1.0f;   // pre-scale Q for exp2 softmax
        const int h = by & 3;
        short8 s0, s1;
        #pragma unroll
        for (int j = 0; j < 8; j++) { s0[j] = f2bf(vals[j]*qs); s1[j] = f2bf(vals[8+j]*qs); }
        short* p = dst + ((size_t)(b*H + h)*T + tl0 + row)*HD + c0;
        *(short8*)p = s0;
        *(short8*)(p + 8) = s1;
    } else if (MODE == 1 || MODE == 3) {
        float* p = of + (size_t)(m0 + row)*256 + n0 + c0;
        #pragma unroll
        for (int jj = 0; jj < 4; jj++) *(float4*)(p + jj*4) = *(float4*)&vals[jj*4];
    } else {
        short8 s0, s1;
        #pragma unroll
        for (int j = 0; j < 8; j++) {
            s0[j] = f2bf(fmaxf(vals[j], 0.f));
            s1[j] = f2bf(fmaxf(vals[8+j], 0.f));
        }
        short* p = o16 + (size_t)(m0 + row)*1024 + n0 + c0;
        *(short8*)p = s0;
        *(short8*)(p + 8) = s1;
    }
}

// ---------------- K2: MFMA flash attention, fixed-max + swapped QK^T -------
// Pass 1: S^T = mfma(K,Q): lane(qr,g) reg r of tile t4 holds S[q=qr][key=16t4+4g+r].
// p = exp2(s) (Q pre-scaled), masked to 0. l = in-lane sum + shfl(16,32).
// P^T repack: 2 cvt_pk + 1 b64 write per tile into Ps[q][key]; A-frag read = b128.
// PV: O^T = mfma(V^T, P^T), identical V-frag reads as before.
__global__ __launch_bounds__(256) void k_flash(
        const short* __restrict__ qb, const short* __restrict__ kb,
        const short* __restrict__ vtb, const float* __restrict__ mask,
        short* __restrict__ attnb, float* __restrict__ part) {
    __shared__ short Ks[64][72];
    __shared__ short Vt[64][72];
    __shared__ short Ps[4][16][72];   // per-wave P[q][key] bf16
    __shared__ float msk[64];
    __shared__ float colacc[4][64];

    const int tid = threadIdx.x;
    const int w = tid >> 6, lane = tid & 63;
    const int qr = lane & 15, g = lane >> 4;
    const int qt = blockIdx.x, h = blockIdx.y, b = blockIdx.z;
    const int bh = b*H + h;
    const int q0 = qt*64 + w*16;

    const short* qg = qb + ((size_t)bh * T + q0) * HD;
    const short8 qf0 = *(const short8*)(qg + qr*HD + g*8);
    const short8 qf1 = *(const short8*)(qg + qr*HD + 32 + g*8);

    const short* kg0 = kb + (size_t)bh * T * HD;
    const short* vg0 = vtb + (size_t)bh * HD * T;
    const float* mg  = mask + (size_t)b * T;
    const int skey = tid >> 2, sc = tid & 3;

    float lrun = 0.f;
    f32x4 oa[4];
    #pragma unroll
    for (int i = 0; i < 4; i++) oa[i] = (f32x4){0.f, 0.f, 0.f, 0.f};

    for (int kt = 0; kt < T/64; kt++) {
        __syncthreads();
        {
            const short* kg = kg0 + (size_t)(kt*64) * HD;
            *(short8*)&Ks[skey][sc*8]      = *(const short8*)(kg + skey*HD + sc*8);
            *(short8*)&Ks[skey][sc*8 + 32] = *(const short8*)(kg + skey*HD + sc*8 + 32);
            const short* vg = vg0 + kt*64;
            *(short8*)&Vt[skey][sc*8]      = *(const short8*)(vg + (size_t)skey*T + sc*8);
            *(short8*)&Vt[skey][sc*8 + 32] = *(const short8*)(vg + (size_t)skey*T + sc*8 + 32);
            if (tid < 64) msk[tid] = mg[kt*64 + tid];
        }
        __syncthreads();

        float p[4][4];
        float lsum = 0.f;
        #pragma unroll
        for (int t4 = 0; t4 < 4; t4++) {
            f32x4 sa = (f32x4){0.f, 0.f, 0.f, 0.f};
            short8 kf0 = *(const short8*)&Ks[t4*16 + qr][g*8];
            short8 kf1 = *(const short8*)&Ks[t4*16 + qr][g*8 + 32];
            sa = __builtin_amdgcn_mfma_f32_16x16x32_bf16(kf0, qf0, sa, 0, 0, 0);
            sa = __builtin_amdgcn_mfma_f32_16x16x32_bf16(kf1, qf1, sa, 0, 0, 0);
            const float4 mv4 = *(const float4*)&msk[t4*16 + 4*g];
            p[t4][0] = (mv4.x > 0.5f) ? 0.f : exp2a(sa[0]);
            p[t4][1] = (mv4.y > 0.5f) ? 0.f : exp2a(sa[1]);
            p[t4][2] = (mv4.z > 0.5f) ? 0.f : exp2a(sa[2]);
            p[t4][3] = (mv4.w > 0.5f) ? 0.f : exp2a(sa[3]);
            lsum += (p[t4][0] + p[t4][1]) + (p[t4][2] + p[t4][3]);
        }
        lsum += __shfl_xor(lsum, 16, 64);
        lsum += __shfl_xor(lsum, 32, 64);
        lrun += lsum;

        #pragma unroll
        for (int t4 = 0; t4 < 4; t4++) {
            union { unsigned u[2]; s16x4 s; } cv;
            cv.u[0] = cvtpk(p[t4][0], p[t4][1]);
            cv.u[1] = cvtpk(p[t4][2], p[t4][3]);
            *(s16x4*)&Ps[w][qr][t4*16 + 4*g] = cv.s;
        }
        asm volatile("" ::: "memory");   // order the punned LDS RAW (R2 lesson)
        const short8 pa0 = *(const short8*)&Ps[w][qr][g*8];
        const short8 pa1 = *(const short8*)&Ps[w][qr][g*8 + 32];

        #pragma unroll
        for (int nt = 0; nt < 4; nt++) {
            short8 vf0 = *(const short8*)&Vt[nt*16 + qr][g*8];
            short8 vf1 = *(const short8*)&Vt[nt*16 + qr][g*8 + 32];
            oa[nt] = __builtin_amdgcn_mfma_f32_16x16x32_bf16(vf0, pa0, oa[nt], 0, 0, 0);
            oa[nt] = __builtin_amdgcn_mfma_f32_16x16x32_bf16(vf1, pa1, oa[nt], 0, 0, 0);
        }
    }

    const float invl = 1.f / lrun;
    #pragma unroll
    for (int nt = 0; nt < 4; nt++) {
        s16x4 pk;
        #pragma unroll
        for (int r = 0; r < 4; r++) pk[r] = f2bf(oa[nt][r] * invl);
        *(s16x4*)&attnb[((size_t)b*T + q0 + qr)*D + h*HD + nt*16 + 4*g] = pk;
    }
    // redistribute invl: pass 2 (unswapped) needs invl at query = 4g+r
    float linv_r[4];
    #pragma unroll
    for (int r = 0; r < 4; r++) linv_r[r] = __shfl(invl, 4*g + r, 64);

    // ---- pass 2: column sums of normalized weights ----
    for (int kt = 0; kt < T/64; kt++) {
        __syncthreads();
        {
            const short* kg = kg0 + (size_t)(kt*64) * HD;
            *(short8*)&Ks[skey][sc*8]      = *(const short8*)(kg + skey*HD + sc*8);
            *(short8*)&Ks[skey][sc*8 + 32] = *(const short8*)(kg + skey*HD + sc*8 + 32);
            if (tid < 64) msk[tid] = mg[kt*64 + tid];
        }
        __syncthreads();
        float cs[4];
        #pragma unroll
        for (int t4 = 0; t4 < 4; t4++) {
            f32x4 sa = (f32x4){0.f, 0.f, 0.f, 0.f};
            short8 kf0 = *(const short8*)&Ks[t4*16 + qr][g*8];
            short8 kf1 = *(const short8*)&Ks[t4*16 + qr][g*8 + 32];
            sa = __builtin_amdgcn_mfma_f32_16x16x32_bf16(qf0, kf0, sa, 0, 0, 0);
            sa = __builtin_amdgcn_mfma_f32_16x16x32_bf16(qf1, kf1, sa, 0, 0, 0);
            float c = exp2a(sa[0])*linv_r[0] + exp2a(sa[1])*linv_r[1]
                    + exp2a(sa[2])*linv_r[2] + exp2a(sa[3])*linv_r[3];
            cs[t4] = (msk[t4*16 + qr] > 0.5f) ? 0.f : c;
        }
        #pragma unroll
        for (int t4 = 0; t4 < 4; t4++) {
            cs[t4] += __shfl_xor(cs[t4], 16, 64);
            cs[t4] += __shfl_xor(cs[t4], 32, 64);
        }
        if (lane < 16) {
            #pragma unroll
            for (int t4 = 0; t4 < 4; t4++) colacc[w][t4*16 + lane] = cs[t4];
        }
        __syncthreads();
        if (tid < 64)
            part[((size_t)bh*32 + qt)*T + kt*64 + tid] =
                colacc[0][tid] + colacc[1][tid] + colacc[2][tid] + colacc[3][tid];
    }
}

// ---------------- K_RED: red[b][k] = sum over 128 (h,qt) rows of part ------
__global__ __launch_bounds__(256) void k_red(
        const float* __restrict__ part, float* __restrict__ red) {
    __shared__ float s[128];
    const int b = blockIdx.y, kc = blockIdx.x;
    const int tid = threadIdx.x;
    const int c = tid & 127, half = tid >> 7;
    const int k = kc*128 + c;
    const float* pb = part + ((size_t)(b*128 + half*64))*T + k;
    float acc = 0.f;
    #pragma unroll 8
    for (int r = 0; r < 64; r++) acc += pb[(size_t)r*T];
    if (half) s[c] = acc;
    __syncthreads();
    if (!half) red[(size_t)b*T + k] = acc + s[c];
}

// ---------------- K3: halting = softmax(red/H + mask*(-1e10)) --------------
__global__ __launch_bounds__(256) void k_halt(
        const float* __restrict__ red, const float* __restrict__ mask,
        float* __restrict__ outh) {
    __shared__ float redm[4], reds[4];
    const int b = blockIdx.x, tid = threadIdx.x;
    const float* mg = mask + (size_t)b * T;
    float v[8];
    float M = -3e38f;
    #pragma unroll
    for (int i = 0; i < 8; i++) {
        v[i] = red[(size_t)b*T + tid + i*256]*0.25f + mg[tid + i*256]*(-1e10f);
        M = fmaxf(M, v[i]);
    }
    #pragma unroll
    for (int off = 1; off < 64; off <<= 1) M = fmaxf(M, __shfl_xor(M, off, 64));
    const int wv = tid >> 6, lane = tid & 63;
    if (lane == 0) redm[wv] = M;
    __syncthreads();
    M = fmaxf(fmaxf(redm[0], redm[1]), fmaxf(redm[2], redm[3]));
    float S = 0.f;
    #pragma unroll
    for (int i = 0; i < 8; i++) { v[i] = __expf(v[i] - M); S += v[i]; }
    #pragma unroll
    for (int off = 1; off < 64; off <<= 1) S += __shfl_xor(S, off, 64);
    if (lane == 0) reds[wv] = S;
    __syncthreads();
    const float invS = 1.f / (reds[0] + reds[1] + reds[2] + reds[3]);
    #pragma unroll
    for (int i = 0; i < 8; i++) outh[(size_t)b*T + tid + i*256] = v[i]*invS;
}

// ---------------- K_LN: y = LN(a + bsrc)*g + be; optional bf16 copy --------
__global__ __launch_bounds__(256) void k_ln(
        const float* __restrict__ a, const float* __restrict__ bsrc,
        const float* __restrict__ g, const float* __restrict__ be,
        float* __restrict__ yf, short* __restrict__ y16) {
    __shared__ float s[16][D];
    const int tid = threadIdx.x;
    const size_t row0 = (size_t)blockIdx.x * 16;
    const float4* ag = (const float4*)(a + row0*D);
    const float4* bg = (const float4*)(bsrc + row0*D);
    #pragma unroll
    for (int i = 0; i < 4; i++) {
        float4 av = ag[tid + i*256], bv = bg[tid + i*256];
        float4 sv = {av.x+bv.x, av.y+bv.y, av.z+bv.z, av.w+bv.w};
        ((float4*)&s[0][0])[tid + i*256] = sv;
    }
    __syncthreads();
    const int wv = tid >> 6, lane = tid & 63;
    float gvv[4], bvv[4];
    #pragma unroll
    for (int s2 = 0; s2 < 4; s2++) { gvv[s2] = g[lane + 64*s2]; bvv[s2] = be[lane + 64*s2]; }
    #pragma unroll
    for (int rr = 0; rr < 4; rr++) {
        const int r = wv*4 + rr;
        float x0 = s[r][lane],     x1 = s[r][lane+64];
        float x2 = s[r][lane+128], x3 = s[r][lane+192];
        float sum = x0+x1+x2+x3;
        float ssq = x0*x0 + x1*x1 + x2*x2 + x3*x3;
        #pragma unroll
        for (int off = 1; off < 64; off <<= 1) {
            sum += __shfl_xor(sum, off, 64);
            ssq += __shfl_xor(ssq, off, 64);
        }
        const float mu = sum * (1.f/256.f);
        const float rs = rsqrtf(ssq*(1.f/256.f) - mu*mu + 1e-5f);
        float y0 = (x0 - mu)*rs*gvv[0] + bvv[0];
        float y1 = (x1 - mu)*rs*gvv[1] + bvv[1];
        float y2 = (x2 - mu)*rs*gvv[2] + bvv[2];
        float y3 = (x3 - mu)*rs*gvv[3] + bvv[3];
        float* yp = yf + (row0 + r)*D;
        yp[lane]     = y0;
        yp[lane+64]  = y1;
        yp[lane+128] = y2;
        yp[lane+192] = y3;
        if (y16) {
            short* hp = y16 + (row0 + r)*D;
            hp[lane]     = f2bf(y0);
            hp[lane+64]  = f2bf(y1);
            hp[lane+128] = f2bf(y2);
            hp[lane+192] = f2bf(y3);
        }
    }
}

} // namespace

extern "C" void kernel_launch(void* const* d_in, const int* in_sizes, int n_in,
                              void* d_out, int out_size, void* d_ws, size_t ws_size,
                              hipStream_t stream) {
    (void)in_sizes; (void)n_in; (void)out_size; (void)ws_size;
    const float* x    = (const float*)d_in[0];
    const float* mask = (const float*)d_in[1];
    const float* Wqkv = (const float*)d_in[2];
    const float* bqkv = (const float*)d_in[3];
    const float* Wo   = (const float*)d_in[4];
    const float* bo   = (const float*)d_in[5];
    const float* W1   = (const float*)d_in[6];
    const float* b1   = (const float*)d_in[7];
    const float* W2   = (const float*)d_in[8];
    const float* b2   = (const float*)d_in[9];
    const float* g1   = (const float*)d_in[10];
    const float* be1  = (const float*)d_in[11];
    const float* g2   = (const float*)d_in[12];
    const float* be2  = (const float*)d_in[13];

    float* out  = (float*)d_out;
    char*  wsb  = (char*)d_ws;
    const size_t MB = 1024*1024;

    short* qb16   = (short*)(wsb + 0*MB);
    short* kb16   = (short*)(wsb + 8*MB);
    short* vt16   = (short*)(wsb + 16*MB);
    short* x16    = (short*)(wsb + 24*MB);
    short* attn16 = (short*)(wsb + 24*MB);
    float* part   = (float*)(wsb + 32*MB);
    float* hb     = (float*)(wsb + 40*MB);
    short* h16    = (short*)(wsb + 56*MB);
    short* wq16   = (short*)(wsb + 64*MB);
    short* wo16   = (short*)(wsb + 64*MB + 393216);
    short* w116   = (short*)(wsb + 64*MB + 524288);
    short* w216   = (short*)(wsb + 64*MB + 1048576);
    float* po     = (float*)(wsb + 66*MB);
    float* fo     = (float*)(wsb + 66*MB);
    short* mid16  = (short*)(wsb + 0*MB);
    float* redb   = (float*)(wsb + 82*MB);
    float* outh   = out + (size_t)B*T*D;

    k_cvt    <<<dim3(1024),        256, 0, stream>>>(x, Wqkv, Wo, W1, W2,
                                                     x16, wq16, wo16, w116, w216);
    k_gemm<0><<<dim3(256, 12),     256, 0, stream>>>(x16, wq16, bqkv, 256,
                                                     qb16, kb16, vt16, nullptr, nullptr);
    k_flash  <<<dim3(T/64, H, B),  256, 0, stream>>>(qb16, kb16, vt16, mask, attn16, part);
    k_red    <<<dim3(16, B),       256, 0, stream>>>(part, redb);
    k_halt   <<<dim3(B),           256, 0, stream>>>(redb, mask, outh);
    k_gemm<1><<<dim3(256, 4),      256, 0, stream>>>(attn16, wo16, bo, 256,
                                                     nullptr, nullptr, nullptr, po, nullptr);
    k_ln     <<<dim3(B*T/16),      256, 0, stream>>>(x, po, g1, be1, hb, h16);
    k_gemm<2><<<dim3(256, 16),     256, 0, stream>>>(h16, w116, b1, 256,
                                                     nullptr, nullptr, nullptr, nullptr, mid16);
    k_gemm<3><<<dim3(256, 4),      256, 0, stream>>>(mid16, w216, b2, 1024,
                                                     nullptr, nullptr, nullptr, fo, nullptr);
    k_ln     <<<dim3(B*T/16),      256, 0, stream>>>(hb, fo, g2, be2, out, nullptr);
}

// Round 6
// 237.604 us; speedup vs baseline: 8.2066x; 1.0156x over previous
//
#include <hip/hip_runtime.h>
#include <hip/hip_bf16.h>
#include <math.h>

namespace {

constexpr int B = 8, T = 2048, D = 256, H = 4, HD = 64, FF = 1024;
constexpr float QSCALE = 0.18033688f;   // 0.125 * log2(e)

typedef __attribute__((ext_vector_type(8))) short short8;
typedef __attribute__((ext_vector_type(4))) short s16x4;
typedef __attribute__((ext_vector_type(4))) float f32x4;

__device__ __forceinline__ short f2bf(float f) {
    __hip_bfloat16 h = __float2bfloat16(f);
    return *reinterpret_cast<short*>(&h);
}
__device__ __forceinline__ float bf2f(short s) {
    union { unsigned u; float f; } c;
    c.u = ((unsigned)(unsigned short)s) << 16;
    return c.f;
}
__device__ __forceinline__ float exp2a(float x) {
    float r; asm("v_exp_f32 %0, %1" : "=v"(r) : "v"(x)); return r;
}
__device__ __forceinline__ unsigned cvtpk(float lo, float hi) {
    unsigned r; asm("v_cvt_pk_bf16_f32 %0, %1, %2" : "=v"(r) : "v"(lo), "v"(hi)); return r;
}

// ---------------- K0: fp32 -> bf16 conversions (x + 4 weight matrices) -----
__global__ __launch_bounds__(256) void k_cvt(
        const float* __restrict__ x,  const float* __restrict__ wq,
        const float* __restrict__ wo, const float* __restrict__ w1,
        const float* __restrict__ w2,
        short* __restrict__ x16,  short* __restrict__ wq16,
        short* __restrict__ wo16, short* __restrict__ w116,
        short* __restrict__ w216) {
    const int N0 = 524288, N1 = 24576, N2 = 8192, N3 = 32768, N4 = 32768;
    const int total = N0 + N1 + N2 + N3 + N4;
    for (int i = blockIdx.x*256 + threadIdx.x; i < total; i += gridDim.x*256) {
        const float* s; short* d; int j = i;
        if (j < N0) { s = x; d = x16; }
        else { j -= N0;
            if (j < N1) { s = wq; d = wq16; }
            else { j -= N1;
                if (j < N2) { s = wo; d = wo16; }
                else { j -= N2;
                    if (j < N3) { s = w1; d = w116; }
                    else { j -= N3; s = w2; d = w216; }
                }
            }
        }
        float4 a = ((const float4*)s)[j*2], b2 = ((const float4*)s)[j*2+1];
        short8 o;
        o[0]=f2bf(a.x);  o[1]=f2bf(a.y);  o[2]=f2bf(a.z);  o[3]=f2bf(a.w);
        o[4]=f2bf(b2.x); o[5]=f2bf(b2.y); o[6]=f2bf(b2.z); o[7]=f2bf(b2.w);
        ((short8*)d)[j] = o;
    }
}

// ---------------- K_GEMM: C[M][N] = A[M][K] * W[N][K]^T, bf16 MFMA ---------
template<int MODE>
__global__ __launch_bounds__(256) void k_gemm(
        const short* __restrict__ A, const short* __restrict__ W,
        const float* __restrict__ bias, const int K,
        short* __restrict__ oq, short* __restrict__ ok, short* __restrict__ ov,
        float* __restrict__ of, short* __restrict__ o16) {
    __shared__ short As[64][72];
    __shared__ short Ws[64][72];
    __shared__ float Cs[64][68];
    const int tid = threadIdx.x;
    const int w = tid >> 6, lane = tid & 63;
    const int qr = lane & 15, g = lane >> 4;
    const int wm = w >> 1, wn = w & 1;
    const int m0 = blockIdx.x * 64;
    const int n0 = blockIdx.y * 64;
    const int srow = tid >> 2, scol = (tid & 3) * 8;
    const short* Ag = A + (size_t)(m0 + srow) * K + scol;
    const short* Wg = W + (size_t)(n0 + srow) * K + scol;

    f32x4 acc[2][2];
    #pragma unroll
    for (int i = 0; i < 2; i++)
        #pragma unroll
        for (int j = 0; j < 2; j++) acc[i][j] = (f32x4){0.f, 0.f, 0.f, 0.f};

    for (int k0 = 0; k0 < K; k0 += 64) {
        __syncthreads();
        *(short8*)&As[srow][scol]      = *(const short8*)(Ag + k0);
        *(short8*)&As[srow][scol + 32] = *(const short8*)(Ag + k0 + 32);
        *(short8*)&Ws[srow][scol]      = *(const short8*)(Wg + k0);
        *(short8*)&Ws[srow][scol + 32] = *(const short8*)(Wg + k0 + 32);
        __syncthreads();
        #pragma unroll
        for (int kk = 0; kk < 2; kk++) {
            short8 a0 = *(const short8*)&As[wm*32 + qr][g*8 + kk*32];
            short8 a1 = *(const short8*)&As[wm*32 + 16 + qr][g*8 + kk*32];
            short8 b0 = *(const short8*)&Ws[wn*32 + qr][g*8 + kk*32];
            short8 b1 = *(const short8*)&Ws[wn*32 + 16 + qr][g*8 + kk*32];
            acc[0][0] = __builtin_amdgcn_mfma_f32_16x16x32_bf16(a0, b0, acc[0][0], 0, 0, 0);
            acc[0][1] = __builtin_amdgcn_mfma_f32_16x16x32_bf16(a0, b1, acc[0][1], 0, 0, 0);
            acc[1][0] = __builtin_amdgcn_mfma_f32_16x16x32_bf16(a1, b0, acc[1][0], 0, 0, 0);
            acc[1][1] = __builtin_amdgcn_mfma_f32_16x16x32_bf16(a1, b1, acc[1][1], 0, 0, 0);
        }
    }

    const int b = m0 >> 11;
    const int tl0 = m0 & (T - 1);

    if (MODE == 0 && blockIdx.y >= 8) {
        const int h = (int)blockIdx.y - 8;
        #pragma unroll
        for (int fm = 0; fm < 2; fm++) {
            const int tbase = tl0 + wm*32 + fm*16 + g*4;
            #pragma unroll
            for (int fn = 0; fn < 2; fn++) {
                const int d = wn*32 + fn*16 + qr;
                const float bv = bias[n0 + d];
                s16x4 pk;
                #pragma unroll
                for (int r = 0; r < 4; r++) pk[r] = f2bf(acc[fm][fn][r] + bv);
                *(s16x4*)&ov[((size_t)(b*H + h)*HD + d)*T + tbase] = pk;
            }
        }
        return;
    }

    #pragma unroll
    for (int fm = 0; fm < 2; fm++)
        #pragma unroll
        for (int fn = 0; fn < 2; fn++)
            #pragma unroll
            for (int r = 0; r < 4; r++)
                Cs[wm*32 + fm*16 + g*4 + r][wn*32 + fn*16 + qr] = acc[fm][fn][r];
    __syncthreads();
    const int row = tid >> 2, c0 = (tid & 3) * 16;
    float vals[16];
    #pragma unroll
    for (int j = 0; j < 16; j++) vals[j] = Cs[row][c0 + j] + bias[n0 + c0 + j];

    if (MODE == 0) {
        const int by = blockIdx.y;
        short* dst = (by < 4) ? oq : ok;
        const float qs = (by < 4) ? QSCALE : 1.0f;
        const int h = by & 3;
        short8 s0, s1;
        #pragma unroll
        for (int j = 0; j < 8; j++) { s0[j] = f2bf(vals[j]*qs); s1[j] = f2bf(vals[8+j]*qs); }
        short* p = dst + ((size_t)(b*H + h)*T + tl0 + row)*HD + c0;
        *(short8*)p = s0;
        *(short8*)(p + 8) = s1;
    } else if (MODE == 1 || MODE == 3) {
        float* p = of + (size_t)(m0 + row)*256 + n0 + c0;
        #pragma unroll
        for (int jj = 0; jj < 4; jj++) *(float4*)(p + jj*4) = *(float4*)&vals[jj*4];
    } else {
        short8 s0, s1;
        #pragma unroll
        for (int j = 0; j < 8; j++) {
            s0[j] = f2bf(fmaxf(vals[j], 0.f));
            s1[j] = f2bf(fmaxf(vals[8+j], 0.f));
        }
        short* p = o16 + (size_t)(m0 + row)*1024 + n0 + c0;
        *(short8*)p = s0;
        *(short8*)(p + 8) = s1;
    }
}

// ---------------- F1: flash pass 1, split-K (partial O_unnorm + partial l) -
// grid: x = qt*2 + khalf (64), y = h, z = b.  Mask folded in as MFMA C-bias.
__global__ __launch_bounds__(256) void k_flash1(
        const short* __restrict__ qb, const short* __restrict__ kb,
        const short* __restrict__ vtb, const float* __restrict__ mask,
        short* __restrict__ opart, float* __restrict__ lpart) {
    __shared__ short Ks[64][72];
    __shared__ short Vt[64][72];
    __shared__ short Ps[4][16][72];
    __shared__ float mskb[64];

    const int tid = threadIdx.x;
    const int w = tid >> 6, lane = tid & 63;
    const int qr = lane & 15, g = lane >> 4;
    const int kh = blockIdx.x & 1, qt = blockIdx.x >> 1;
    const int h = blockIdx.y, b = blockIdx.z;
    const int bh = b*H + h;
    const int q0 = qt*64 + w*16;

    const short* qg = qb + ((size_t)bh * T + q0) * HD;
    const short8 qf0 = *(const short8*)(qg + qr*HD + g*8);
    const short8 qf1 = *(const short8*)(qg + qr*HD + 32 + g*8);

    const short* kg0 = kb + (size_t)bh * T * HD + (size_t)kh * 1024 * HD;
    const short* vg0 = vtb + (size_t)bh * HD * T + kh * 1024;
    const float* mg  = mask + (size_t)b * T + kh * 1024;
    const int skey = tid >> 2, sc = tid & 3;

    float lrun = 0.f;
    f32x4 oa[4];
    #pragma unroll
    for (int i = 0; i < 4; i++) oa[i] = (f32x4){0.f, 0.f, 0.f, 0.f};

    for (int kt = 0; kt < 16; kt++) {
        __syncthreads();
        {
            const short* kg = kg0 + (size_t)(kt*64) * HD;
            *(short8*)&Ks[skey][sc*8]      = *(const short8*)(kg + skey*HD + sc*8);
            *(short8*)&Ks[skey][sc*8 + 32] = *(const short8*)(kg + skey*HD + sc*8 + 32);
            const short* vg = vg0 + kt*64;
            *(short8*)&Vt[skey][sc*8]      = *(const short8*)(vg + (size_t)skey*T + sc*8);
            *(short8*)&Vt[skey][sc*8 + 32] = *(const short8*)(vg + (size_t)skey*T + sc*8 + 32);
            if (tid < 64) mskb[tid] = (mg[kt*64 + tid] > 0.5f) ? -1e9f : 0.f;
        }
        __syncthreads();

        float p[4][4];
        float lsum = 0.f;
        #pragma unroll
        for (int t4 = 0; t4 < 4; t4++) {
            const float4 mb4 = *(const float4*)&mskb[t4*16 + 4*g];
            f32x4 sa = (f32x4){mb4.x, mb4.y, mb4.z, mb4.w};   // mask bias as C-in
            short8 kf0 = *(const short8*)&Ks[t4*16 + qr][g*8];
            short8 kf1 = *(const short8*)&Ks[t4*16 + qr][g*8 + 32];
            sa = __builtin_amdgcn_mfma_f32_16x16x32_bf16(kf0, qf0, sa, 0, 0, 0);
            sa = __builtin_amdgcn_mfma_f32_16x16x32_bf16(kf1, qf1, sa, 0, 0, 0);
            p[t4][0] = exp2a(sa[0]);
            p[t4][1] = exp2a(sa[1]);
            p[t4][2] = exp2a(sa[2]);
            p[t4][3] = exp2a(sa[3]);
            lsum += (p[t4][0] + p[t4][1]) + (p[t4][2] + p[t4][3]);
        }
        lsum += __shfl_xor(lsum, 16, 64);
        lsum += __shfl_xor(lsum, 32, 64);
        lrun += lsum;

        #pragma unroll
        for (int t4 = 0; t4 < 4; t4++) {
            union { unsigned u[2]; s16x4 s; } cv;
            cv.u[0] = cvtpk(p[t4][0], p[t4][1]);
            cv.u[1] = cvtpk(p[t4][2], p[t4][3]);
            *(s16x4*)&Ps[w][qr][t4*16 + 4*g] = cv.s;
        }
        asm volatile("" ::: "memory");   // order the punned LDS RAW (R2 lesson)
        const short8 pa0 = *(const short8*)&Ps[w][qr][g*8];
        const short8 pa1 = *(const short8*)&Ps[w][qr][g*8 + 32];

        #pragma unroll
        for (int nt = 0; nt < 4; nt++) {
            short8 vf0 = *(const short8*)&Vt[nt*16 + qr][g*8];
            short8 vf1 = *(const short8*)&Vt[nt*16 + qr][g*8 + 32];
            oa[nt] = __builtin_amdgcn_mfma_f32_16x16x32_bf16(vf0, pa0, oa[nt], 0, 0, 0);
            oa[nt] = __builtin_amdgcn_mfma_f32_16x16x32_bf16(vf1, pa1, oa[nt], 0, 0, 0);
        }
    }

    const size_t obase = ((size_t)(kh*32 + bh)*2048 + q0 + qr) * 64;
    #pragma unroll
    for (int nt = 0; nt < 4; nt++) {
        s16x4 pk;
        #pragma unroll
        for (int r = 0; r < 4; r++) pk[r] = f2bf(oa[nt][r]);
        *(s16x4*)&opart[obase + nt*16 + 4*g] = pk;
    }
    if (lane < 16)
        lpart[(size_t)(kh*32 + bh)*2048 + q0 + qr] = lrun;
}

// ---------------- COMB: O = (O0+O1)/(l0+l1) -> attn16; invl to global ------
__global__ __launch_bounds__(256) void k_comb(
        const short* __restrict__ opart, const float* __restrict__ lpart,
        short* __restrict__ attnb, float* __restrict__ invlb) {
    const int j = blockIdx.x*256 + threadIdx.x;
    const size_t flat = (size_t)j * 8;
    const int d0 = (int)(flat & 63);
    const int q  = (int)((flat >> 6) & 2047);
    const int bh = (int)(flat >> 17);
    short8 o0 = *(const short8*)&opart[flat];
    short8 o1 = *(const short8*)&opart[flat + (size_t)4194304];
    const float l = lpart[bh*2048 + q] + lpart[65536 + bh*2048 + q];
    const float inv = 1.f / l;
    short8 r;
    #pragma unroll
    for (int i = 0; i < 8; i++) r[i] = f2bf((bf2f(o0[i]) + bf2f(o1[i])) * inv);
    const int b = bh >> 2, h = bh & 3;
    *(short8*)&attnb[((size_t)(b*2048 + q))*256 + h*64 + d0] = r;
    if (d0 == 0) invlb[bh*2048 + q] = inv;
}

// ---------------- F2: colsum pass, split-K, tiny LDS, full occupancy -------
__global__ __launch_bounds__(256) void k_flash2(
        const short* __restrict__ qb, const short* __restrict__ kb,
        const float* __restrict__ mask, const float* __restrict__ invlb,
        float* __restrict__ part) {
    __shared__ short Ks[64][72];
    __shared__ float mskb[64];
    __shared__ float colacc[4][64];

    const int tid = threadIdx.x;
    const int w = tid >> 6, lane = tid & 63;
    const int qr = lane & 15, g = lane >> 4;
    const int kh = blockIdx.x & 1, qt = blockIdx.x >> 1;
    const int h = blockIdx.y, b = blockIdx.z;
    const int bh = b*H + h;
    const int q0 = qt*64 + w*16;

    const short* qg = qb + ((size_t)bh * T + q0) * HD;
    const short8 qf0 = *(const short8*)(qg + qr*HD + g*8);
    const short8 qf1 = *(const short8*)(qg + qr*HD + 32 + g*8);

    float linv[4];
    #pragma unroll
    for (int r = 0; r < 4; r++) linv[r] = invlb[bh*2048 + q0 + 4*g + r];

    const short* kg0 = kb + (size_t)bh * T * HD + (size_t)kh * 1024 * HD;
    const float* mg  = mask + (size_t)b * T + kh * 1024;
    const int skey = tid >> 2, sc = tid & 3;

    for (int kt = 0; kt < 16; kt++) {
        __syncthreads();
        {
            const short* kg = kg0 + (size_t)(kt*64) * HD;
            *(short8*)&Ks[skey][sc*8]      = *(const short8*)(kg + skey*HD + sc*8);
            *(short8*)&Ks[skey][sc*8 + 32] = *(const short8*)(kg + skey*HD + sc*8 + 32);
            if (tid < 64) mskb[tid] = (mg[kt*64 + tid] > 0.5f) ? -1e9f : 0.f;
        }
        __syncthreads();
        float cs[4];
        #pragma unroll
        for (int t4 = 0; t4 < 4; t4++) {
            const float mb = mskb[t4*16 + qr];
            f32x4 sa = (f32x4){mb, mb, mb, mb};   // key-mask bias as C-in
            short8 kf0 = *(const short8*)&Ks[t4*16 + qr][g*8];
            short8 kf1 = *(const short8*)&Ks[t4*16 + qr][g*8 + 32];
            sa = __builtin_amdgcn_mfma_f32_16x16x32_bf16(qf0, kf0, sa, 0, 0, 0);
            sa = __builtin_amdgcn_mfma_f32_16x16x32_bf16(qf1, kf1, sa, 0, 0, 0);
            cs[t4] = exp2a(sa[0])*linv[0] + exp2a(sa[1])*linv[1]
                   + exp2a(sa[2])*linv[2] + exp2a(sa[3])*linv[3];
        }
        #pragma unroll
        for (int t4 = 0; t4 < 4; t4++) {
            cs[t4] += __shfl_xor(cs[t4], 16, 64);
            cs[t4] += __shfl_xor(cs[t4], 32, 64);
        }
        if (lane < 16) {
            #pragma unroll
            for (int t4 = 0; t4 < 4; t4++) colacc[w][t4*16 + lane] = cs[t4];
        }
        __syncthreads();
        if (tid < 64)
            part[((size_t)bh*32 + qt)*T + kh*1024 + kt*64 + tid] =
                colacc[0][tid] + colacc[1][tid] + colacc[2][tid] + colacc[3][tid];
    }
}

// ---------------- K_RED: red[b][k] = sum over 128 (h,qt) rows of part ------
__global__ __launch_bounds__(256) void k_red(
        const float* __restrict__ part, float* __restrict__ red) {
    __shared__ float s[128];
    const int b = blockIdx.y, kc = blockIdx.x;
    const int tid = threadIdx.x;
    const int c = tid & 127, half = tid >> 7;
    const int k = kc*128 + c;
    const float* pb = part + ((size_t)(b*128 + half*64))*T + k;
    float acc = 0.f;
    #pragma unroll 8
    for (int r = 0; r < 64; r++) acc += pb[(size_t)r*T];
    if (half) s[c] = acc;
    __syncthreads();
    if (!half) red[(size_t)b*T + k] = acc + s[c];
}

// ---------------- K3: halting = softmax(red/H + mask*(-1e10)) --------------
__global__ __launch_bounds__(256) void k_halt(
        const float* __restrict__ red, const float* __restrict__ mask,
        float* __restrict__ outh) {
    __shared__ float redm[4], reds[4];
    const int b = blockIdx.x, tid = threadIdx.x;
    const float* mg = mask + (size_t)b * T;
    float v[8];
    float M = -3e38f;
    #pragma unroll
    for (int i = 0; i < 8; i++) {
        v[i] = red[(size_t)b*T + tid + i*256]*0.25f + mg[tid + i*256]*(-1e10f);
        M = fmaxf(M, v[i]);
    }
    #pragma unroll
    for (int off = 1; off < 64; off <<= 1) M = fmaxf(M, __shfl_xor(M, off, 64));
    const int wv = tid >> 6, lane = tid & 63;
    if (lane == 0) redm[wv] = M;
    __syncthreads();
    M = fmaxf(fmaxf(redm[0], redm[1]), fmaxf(redm[2], redm[3]));
    float S = 0.f;
    #pragma unroll
    for (int i = 0; i < 8; i++) { v[i] = __expf(v[i] - M); S += v[i]; }
    #pragma unroll
    for (int off = 1; off < 64; off <<= 1) S += __shfl_xor(S, off, 64);
    if (lane == 0) reds[wv] = S;
    __syncthreads();
    const float invS = 1.f / (reds[0] + reds[1] + reds[2] + reds[3]);
    #pragma unroll
    for (int i = 0; i < 8; i++) outh[(size_t)b*T + tid + i*256] = v[i]*invS;
}

// ---------------- K_LN: y = LN(a + bsrc)*g + be; optional bf16 copy --------
__global__ __launch_bounds__(256) void k_ln(
        const float* __restrict__ a, const float* __restrict__ bsrc,
        const float* __restrict__ g, const float* __restrict__ be,
        float* __restrict__ yf, short* __restrict__ y16) {
    __shared__ float s[16][D];
    const int tid = threadIdx.x;
    const size_t row0 = (size_t)blockIdx.x * 16;
    const float4* ag = (const float4*)(a + row0*D);
    const float4* bg = (const float4*)(bsrc + row0*D);
    #pragma unroll
    for (int i = 0; i < 4; i++) {
        float4 av = ag[tid + i*256], bv = bg[tid + i*256];
        float4 sv = {av.x+bv.x, av.y+bv.y, av.z+bv.z, av.w+bv.w};
        ((float4*)&s[0][0])[tid + i*256] = sv;
    }
    __syncthreads();
    const int wv = tid >> 6, lane = tid & 63;
    float gvv[4], bvv[4];
    #pragma unroll
    for (int s2 = 0; s2 < 4; s2++) { gvv[s2] = g[lane + 64*s2]; bvv[s2] = be[lane + 64*s2]; }
    #pragma unroll
    for (int rr = 0; rr < 4; rr++) {
        const int r = wv*4 + rr;
        float x0 = s[r][lane],     x1 = s[r][lane+64];
        float x2 = s[r][lane+128], x3 = s[r][lane+192];
        float sum = x0+x1+x2+x3;
        float ssq = x0*x0 + x1*x1 + x2*x2 + x3*x3;
        #pragma unroll
        for (int off = 1; off < 64; off <<= 1) {
            sum += __shfl_xor(sum, off, 64);
            ssq += __shfl_xor(ssq, off, 64);
        }
        const float mu = sum * (1.f/256.f);
        const float rs = rsqrtf(ssq*(1.f/256.f) - mu*mu + 1e-5f);
        float y0 = (x0 - mu)*rs*gvv[0] + bvv[0];
        float y1 = (x1 - mu)*rs*gvv[1] + bvv[1];
        float y2 = (x2 - mu)*rs*gvv[2] + bvv[2];
        float y3 = (x3 - mu)*rs*gvv[3] + bvv[3];
        float* yp = yf + (row0 + r)*D;
        yp[lane]     = y0;
        yp[lane+64]  = y1;
        yp[lane+128] = y2;
        yp[lane+192] = y3;
        if (y16) {
            short* hp = y16 + (row0 + r)*D;
            hp[lane]     = f2bf(y0);
            hp[lane+64]  = f2bf(y1);
            hp[lane+128] = f2bf(y2);
            hp[lane+192] = f2bf(y3);
        }
    }
}

} // namespace

extern "C" void kernel_launch(void* const* d_in, const int* in_sizes, int n_in,
                              void* d_out, int out_size, void* d_ws, size_t ws_size,
                              hipStream_t stream) {
    (void)in_sizes; (void)n_in; (void)out_size; (void)ws_size;
    const float* x    = (const float*)d_in[0];
    const float* mask = (const float*)d_in[1];
    const float* Wqkv = (const float*)d_in[2];
    const float* bqkv = (const float*)d_in[3];
    const float* Wo   = (const float*)d_in[4];
    const float* bo   = (const float*)d_in[5];
    const float* W1   = (const float*)d_in[6];
    const float* b1   = (const float*)d_in[7];
    const float* W2   = (const float*)d_in[8];
    const float* b2   = (const float*)d_in[9];
    const float* g1   = (const float*)d_in[10];
    const float* be1  = (const float*)d_in[11];
    const float* g2   = (const float*)d_in[12];
    const float* be2  = (const float*)d_in[13];

    float* out  = (float*)d_out;
    char*  wsb  = (char*)d_ws;
    const size_t MB = 1024*1024;

    // liveness-overlaid layout, top = 91 MiB (96 MiB proven available in R1)
    short* qb16   = (short*)(wsb + 0*MB);            // live gemm0 -> flash2
    short* kb16   = (short*)(wsb + 8*MB);            // live gemm0 -> flash2
    short* vt16   = (short*)(wsb + 16*MB);           // live gemm0 -> flash1
    short* x16    = (short*)(wsb + 24*MB);           // dead after gemm0
    short* attn16 = (short*)(wsb + 24*MB);           // comb -> gemm1
    short* opart  = (short*)(wsb + 32*MB);           // 16MB, flash1 -> comb
    float* part   = (float*)(wsb + 32*MB);           // 8MB, flash2 -> red (opart dead)
    float* redb   = (float*)(wsb + 40*MB);           // 64KB, red -> halt
    float* hb     = (float*)(wsb + 48*MB);           // ln1 -> ln2
    short* h16    = (short*)(wsb + 64*MB);           // ln1 -> ffn1
    float* lpart  = (float*)(wsb + 72*MB);           // 512KB, flash1 -> comb
    float* invlb  = (float*)(wsb + 72*MB + 524288);  // 256KB, comb -> flash2
    short* wq16   = (short*)(wsb + 73*MB);
    short* wo16   = (short*)(wsb + 73*MB + 393216);
    short* w116   = (short*)(wsb + 73*MB + 524288);
    short* w216   = (short*)(wsb + 73*MB + 1048576);
    float* po     = (float*)(wsb + 75*MB);           // gemm1 -> ln1
    float* fo     = (float*)(wsb + 75*MB);           // gemm3 -> ln2 (po dead)
    short* mid16  = (short*)(wsb + 0*MB);            // ffn1 -> ffn2 (q/k/v/attn dead)
    float* outh   = out + (size_t)B*T*D;

    k_cvt    <<<dim3(1024),        256, 0, stream>>>(x, Wqkv, Wo, W1, W2,
                                                     x16, wq16, wo16, w116, w216);
    k_gemm<0><<<dim3(256, 12),     256, 0, stream>>>(x16, wq16, bqkv, 256,
                                                     qb16, kb16, vt16, nullptr, nullptr);
    k_flash1 <<<dim3(64, H, B),    256, 0, stream>>>(qb16, kb16, vt16, mask, opart, lpart);
    k_comb   <<<dim3(2048),        256, 0, stream>>>(opart, lpart, attn16, invlb);
    k_flash2 <<<dim3(64, H, B),    256, 0, stream>>>(qb16, kb16, mask, invlb, part);
    k_red    <<<dim3(16, B),       256, 0, stream>>>(part, redb);
    k_halt   <<<dim3(B),           256, 0, stream>>>(redb, mask, outh);
    k_gemm<1><<<dim3(256, 4),      256, 0, stream>>>(attn16, wo16, bo, 256,
                                                     nullptr, nullptr, nullptr, po, nullptr);
    k_ln     <<<dim3(B*T/16),      256, 0, stream>>>(x, po, g1, be1, hb, h16);
    k_gemm<2><<<dim3(256, 16),     256, 0, stream>>>(h16, w116, b1, 256,
                                                     nullptr, nullptr, nullptr, nullptr, mid16);
    k_gemm<3><<<dim3(256, 4),      256, 0, stream>>>(mid16, w216, b2, 1024,
                                                     nullptr, nullptr, nullptr, fo, nullptr);
    k_ln     <<<dim3(B*T/16),      256, 0, stream>>>(hb, fo, g2, be2, out, nullptr);
}